// Round 22
// baseline (206.611 us; speedup 1.0000x reference)
//
#include <hip/hip_runtime.h>
#include <hip/hip_bf16.h>

static constexpr int TOTAL = 349525;
static constexpr int OFFS[11] = {0,1,5,21,85,341,1365,5461,21845,87381,349525};
static constexpr size_t CONV_USH = (size_t)8*9*2*4*64*8;    // 294912 ushorts
static constexpr size_t EMB_USH  = (size_t)10*2*4*64*8;     //  40960 ushorts
static constexpr size_t FRAG_USH = CONV_USH + EMB_USH;      // 335872
static constexpr size_t FRAG_BYTES = FRAG_USH*2*2;          // 1343488 B
static constexpr size_t HPRE_BYTES = (size_t)(87381-85)*64*4;
static constexpr int WPREP_BLOCKS = 164;
static constexpr int INPROJ_BLOCKS = (TOTAL + 127)/128;     // 2731

typedef __attribute__((ext_vector_type(8))) short short8;
typedef __attribute__((ext_vector_type(4))) float f32x4;

__device__ __forceinline__ unsigned deint(unsigned v){
  v &= 0x55555555u;
  v = (v | (v>>1)) & 0x33333333u;
  v = (v | (v>>2)) & 0x0F0F0F0Fu;
  v = (v | (v>>4)) & 0x00FF00FFu;
  v = (v | (v>>8)) & 0x0000FFFFu;
  return v;
}
__device__ __forceinline__ unsigned ileave(unsigned v){
  v &= 0xFFFFu;
  v = (v | (v<<8)) & 0x00FF00FFu;
  v = (v | (v<<4)) & 0x0F0F0F0Fu;
  v = (v | (v<<2)) & 0x33333333u;
  v = (v | (v<<1)) & 0x55555555u;
  return v;
}
__device__ __forceinline__ unsigned short f2bh(float x){
  unsigned u = __float_as_uint(x);
  return (unsigned short)((u + 0x7FFFu + ((u>>16)&1u)) >> 16);
}
__device__ __forceinline__ float bh2f(unsigned short h){
  return __uint_as_float(((unsigned)h) << 16);
}
__device__ __forceinline__ void split8(float4 a, float4 b, short8 &hi, short8 &lo){
  float v[8] = {a.x,a.y,a.z,a.w,b.x,b.y,b.z,b.w};
  unsigned short hv[8], lv[8];
  #pragma unroll
  for (int j=0;j<8;++j){ hv[j]=f2bh(v[j]); lv[j]=f2bh(v[j]-bh2f(hv[j])); }
  hi = short8{(short)hv[0],(short)hv[1],(short)hv[2],(short)hv[3],
              (short)hv[4],(short)hv[5],(short)hv[6],(short)hv[7]};
  lo = short8{(short)lv[0],(short)lv[1],(short)lv[2],(short)lv[3],
              (short)lv[4],(short)lv[5],(short)lv[6],(short)lv[7]};
}

// ---------- merged prep: blocks <164 = W-frag prep; rest = inproj (verified) ----------
__global__ __launch_bounds__(256) void k_prep(const float* __restrict__ convW,
    const float* __restrict__ embW,
    unsigned short* __restrict__ WH, unsigned short* __restrict__ WLo,
    const float* __restrict__ feat, const float* __restrict__ ipW,
    const float* __restrict__ ipB, float* __restrict__ h,
    float* __restrict__ hpre){
  __shared__ float Alt[128][44];
  __shared__ float Wl[40][68];
  int t = threadIdx.x;
  if ((int)blockIdx.x < WPREP_BLOCKS){
    int tid = blockIdx.x*256 + t;
    if (tid >= 41984) return;
    const float* src;
    size_t dst;
    if (tid < 36864){
      int l=tid&63, cb=(tid>>6)&3, ks=(tid>>8)&1;
      int x=tid>>9; int m=x%9, Lp=x/9;
      int k0=ks*32+((l>>4)<<3), ch=cb*16+(l&15);
      src = convW + (size_t)(Lp+1)*36864 + (size_t)(m*64+k0)*64 + ch;
      dst = (size_t)tid*8;
    } else {
      int t2 = tid - 36864;
      int l=t2&63, cb=(t2>>6)&3, ks=(t2>>8)&1, d=t2>>9;
      int k0=ks*32+((l>>4)<<3), ch=cb*16+(l&15);
      src = embW + (size_t)d*4096 + (size_t)k0*64 + ch;
      dst = CONV_USH + (size_t)t2*8;
    }
    unsigned short hv[8], lv[8];
    #pragma unroll
    for (int j=0;j<8;++j){
      float v = src[(size_t)j*64];
      unsigned short hh = f2bh(v);
      hv[j] = hh;
      lv[j] = f2bh(v - bh2f(hh));
    }
    short8 vh = {(short)hv[0],(short)hv[1],(short)hv[2],(short)hv[3],
                 (short)hv[4],(short)hv[5],(short)hv[6],(short)hv[7]};
    short8 vl = {(short)lv[0],(short)lv[1],(short)lv[2],(short)lv[3],
                 (short)lv[4],(short)lv[5],(short)lv[6],(short)lv[7]};
    *(short8*)(WH  + dst) = vh;
    *(short8*)(WLo + dst) = vl;
    return;
  }
  int base = ((int)blockIdx.x - WPREP_BLOCKS) * 128;
  for (int idx = t; idx < 40*64; idx += 256)
    Wl[idx >> 6][idx & 63] = ipW[idx];
  if (t < 128){
    int g = base + t;
    float* row = Alt[t];
    if (g < TOTAL){
      int d = 0;
      #pragma unroll
      for (int i = 1; i <= 9; ++i) if (g >= OFFS[i]) d = i;
      int local = g - OFFS[d];
      unsigned ix = deint((unsigned)local), iy = deint(((unsigned)local) >> 1);
      float inv = 1.0f / (float)(1 << d);
      float px = ((float)ix + 0.5f) * inv;
      float py = ((float)iy + 0.5f) * inv;
      float pd = (float)d * (1.0f/9.0f);
      row[0] = feat[g]; row[1] = px; row[2] = py; row[3] = pd;
      float p3[3] = {px, py, pd};
      #pragma unroll
      for (int c = 0; c < 3; ++c){
        float s, co;
        __sincosf(6.28318530717958647692f * p3[c], &s, &co);
        float* rb = row + 4 + c*12;
        #pragma unroll
        for (int f = 0; f < 6; ++f){
          rb[f] = s; rb[6+f] = co;
          float s2 = 2.f*s*co, c2 = 1.f - 2.f*s*s;
          s = s2; co = c2;
        }
      }
    } else {
      #pragma unroll
      for (int k = 0; k < 40; ++k) row[k] = 0.f;
    }
  }
  __syncthreads();
  int tr = t >> 3, tc = t & 7;
  float acc[4][8];
  #pragma unroll
  for (int i=0;i<4;++i)
    #pragma unroll
    for (int c=0;c<8;++c) acc[i][c] = 0.f;
  #pragma unroll 2
  for (int k4 = 0; k4 < 10; ++k4){
    float av4[4][4];
    #pragma unroll
    for (int i=0;i<4;++i){
      float4 aa = *(const float4*)&Alt[tr*4+i][k4*4];
      av4[i][0]=aa.x; av4[i][1]=aa.y; av4[i][2]=aa.z; av4[i][3]=aa.w;
    }
    #pragma unroll
    for (int j=0;j<4;++j){
      float4 lo = *(const float4*)&Wl[k4*4+j][tc*8];
      float4 hi = *(const float4*)&Wl[k4*4+j][tc*8+4];
      float wv[8];
      wv[0]=lo.x; wv[1]=lo.y; wv[2]=lo.z; wv[3]=lo.w;
      wv[4]=hi.x; wv[5]=hi.y; wv[6]=hi.z; wv[7]=hi.w;
      #pragma unroll
      for (int i=0;i<4;++i){
        float a = av4[i][j];
        #pragma unroll
        for (int c=0;c<8;++c) acc[i][c] += a*wv[c];
      }
    }
  }
  #pragma unroll
  for (int i=0;i<4;++i){
    int g = base + tr*4 + i;
    if (g >= TOTAL) continue;
    float ov[8];
    #pragma unroll
    for (int c=0;c<8;++c) ov[c] = acc[i][c] + ipB[tc*8+c];
    float* dst = &h[(size_t)g*64 + tc*8];
    *(float4*)dst       = *(const float4*)&ov[0];
    *(float4*)(dst + 4) = *(const float4*)&ov[4];
    if (hpre && g >= OFFS[4] && g < OFFS[9]){
      float* dp = hpre + (size_t)(g - OFFS[4])*64 + tc*8;
      *(float4*)dp       = *(const float4*)&ov[0];
      *(float4*)(dp + 4) = *(const float4*)&ov[4];
    }
  }
}

// ---------- conv body (verified): halo + fused pool + MFMA bf16-split ----------
__device__ __forceinline__ void conv_dev(float* __restrict__ h,
    const float* __restrict__ hPar,
    const unsigned short* __restrict__ WHl, const unsigned short* __restrict__ WLl,
    const float* __restrict__ Bb, int N, int offL, int offC, int lbits, int bnum,
    unsigned short* haloH, unsigned short* haloL, int* hkey, int t){
  int nb = bnum * 64;
  int res = 1 << lbits;
  if (t < 100){
    int i = t % 10, j = t / 10;
    int gx = (int)deint((unsigned)nb) - 1 + i;
    int gy = (int)deint(((unsigned)nb)>>1) - 1 + j;
    bool ok = (gx>=0 && gy>=0 && gx<res && gy<res);
    hkey[t] = ok ? (int)(ileave((unsigned)gx) | (ileave((unsigned)gy)<<1)) : -1;
  }
  __syncthreads();
  const float* hC = h + (size_t)offC*64;
  for (int e = t; e < 1600; e += 256){
    int hi_ = e >> 4, u = e & 15;
    int key = hkey[hi_];
    float4 r = make_float4(0.f,0.f,0.f,0.f);
    if (key >= 0){
      const float4* c = (const float4*)(hC + (size_t)(4*key)*64) + u;
      float4 c0 = c[0], c1 = c[16], c2 = c[32], c3 = c[48];
      float4 pr = *((const float4*)(hPar + (size_t)key*64) + u);
      r.x = 0.25f*(c0.x+c1.x+c2.x+c3.x) + pr.x;
      r.y = 0.25f*(c0.y+c1.y+c2.y+c3.y) + pr.y;
      r.z = 0.25f*(c0.z+c1.z+c2.z+c3.z) + pr.z;
      r.w = 0.25f*(c0.w+c1.w+c2.w+c3.w) + pr.w;
    }
    unsigned short h0=f2bh(r.x), h1=f2bh(r.y), h2=f2bh(r.z), h3=f2bh(r.w);
    *(ushort4*)&haloH[hi_*72 + u*4] = make_ushort4(h0,h1,h2,h3);
    *(ushort4*)&haloL[hi_*72 + u*4] = make_ushort4(
        f2bh(r.x - bh2f(h0)), f2bh(r.y - bh2f(h1)),
        f2bh(r.z - bh2f(h2)), f2bh(r.w - bh2f(h3)));
  }
  __syncthreads();
  int cb   = __builtin_amdgcn_readfirstlane(t >> 6);
  int lane = t & 63;
  int q = lane >> 4;
  int chl = cb*16 + (lane & 15);
  int lx0,ly0,lx1,ly1,lx2,ly2,lx3,ly3;
  {
    int n0 = (lane&15), n1 = 16+(lane&15), n2 = 32+(lane&15), n3 = 48+(lane&15);
    lx0=(int)deint((unsigned)n0); ly0=(int)deint(((unsigned)n0)>>1);
    lx1=(int)deint((unsigned)n1); ly1=(int)deint(((unsigned)n1)>>1);
    lx2=(int)deint((unsigned)n2); ly2=(int)deint(((unsigned)n2)>>1);
    lx3=(int)deint((unsigned)n3); ly3=(int)deint(((unsigned)n3)>>1);
  }
  f32x4 acc0 = {0.f,0.f,0.f,0.f}, acc1 = acc0, acc2 = acc0, acc3 = acc0;
  #pragma unroll 1
  for (int dy=0;dy<3;++dy){
    #pragma unroll 1
    for (int dx=0;dx<3;++dx){
      int m = dy*3 + dx;
      int r0 = (ly0+dy)*10 + lx0+dx;
      int r1 = (ly1+dy)*10 + lx1+dx;
      int r2 = (ly2+dy)*10 + lx2+dx;
      int r3 = (ly3+dy)*10 + lx3+dx;
      #pragma unroll
      for (int ks=0;ks<2;++ks){
        const unsigned short* fp = WHl + ((size_t)((m*2+ks)*4 + cb)*64 + lane)*8;
        const unsigned short* fq = WLl + ((size_t)((m*2+ks)*4 + cb)*64 + lane)*8;
        short8 bh = *(const short8*)fp;
        short8 bl = *(const short8*)fq;
        int so = (ks*4 + q)*8;
        short8 ah0 = *(const short8*)&haloH[r0*72 + so];
        short8 al0 = *(const short8*)&haloL[r0*72 + so];
        short8 ah1 = *(const short8*)&haloH[r1*72 + so];
        short8 al1 = *(const short8*)&haloL[r1*72 + so];
        short8 ah2 = *(const short8*)&haloH[r2*72 + so];
        short8 al2 = *(const short8*)&haloL[r2*72 + so];
        short8 ah3 = *(const short8*)&haloH[r3*72 + so];
        short8 al3 = *(const short8*)&haloL[r3*72 + so];
        acc0 = __builtin_amdgcn_mfma_f32_16x16x32_bf16(ah0, bh, acc0, 0,0,0);
        acc1 = __builtin_amdgcn_mfma_f32_16x16x32_bf16(ah1, bh, acc1, 0,0,0);
        acc2 = __builtin_amdgcn_mfma_f32_16x16x32_bf16(ah2, bh, acc2, 0,0,0);
        acc3 = __builtin_amdgcn_mfma_f32_16x16x32_bf16(ah3, bh, acc3, 0,0,0);
        acc0 = __builtin_amdgcn_mfma_f32_16x16x32_bf16(al0, bh, acc0, 0,0,0);
        acc1 = __builtin_amdgcn_mfma_f32_16x16x32_bf16(al1, bh, acc1, 0,0,0);
        acc2 = __builtin_amdgcn_mfma_f32_16x16x32_bf16(al2, bh, acc2, 0,0,0);
        acc3 = __builtin_amdgcn_mfma_f32_16x16x32_bf16(al3, bh, acc3, 0,0,0);
        acc0 = __builtin_amdgcn_mfma_f32_16x16x32_bf16(ah0, bl, acc0, 0,0,0);
        acc1 = __builtin_amdgcn_mfma_f32_16x16x32_bf16(ah1, bl, acc1, 0,0,0);
        acc2 = __builtin_amdgcn_mfma_f32_16x16x32_bf16(ah2, bl, acc2, 0,0,0);
        acc3 = __builtin_amdgcn_mfma_f32_16x16x32_bf16(ah3, bl, acc3, 0,0,0);
      }
    }
  }
  float bias = Bb[chl];
  int rowb = q*4;
  float* hO = h + (size_t)(offL + nb)*64;
  #pragma unroll
  for (int reg=0;reg<4;++reg){
    int n0 = rowb + reg;
    float v0 = acc0[reg] + bias; if (nb + n0      < N) hO[(size_t)(n0     )*64 + chl] = v0 > 0.f ? v0 : 0.f;
    float v1 = acc1[reg] + bias; if (nb + n0 + 16 < N) hO[(size_t)(n0 + 16)*64 + chl] = v1 > 0.f ? v1 : 0.f;
    float v2 = acc2[reg] + bias; if (nb + n0 + 32 < N) hO[(size_t)(n0 + 32)*64 + chl] = v2 > 0.f ? v2 : 0.f;
    float v3 = acc3[reg] + bias; if (nb + n0 + 48 < N) hO[(size_t)(n0 + 48)*64 + chl] = v3 > 0.f ? v3 : 0.f;
  }
}

// ---------- conv launch (bare) ----------
__global__ __launch_bounds__(256) void k_conv(float* __restrict__ h,
    const float* __restrict__ hPar,
    const unsigned short* __restrict__ WHl, const unsigned short* __restrict__ WLl,
    const float* __restrict__ Bb, int N, int offL, int offC, int lbits){
  __shared__ unsigned short haloH[100*72];
  __shared__ unsigned short haloL[100*72];
  __shared__ int hkey[100];
  conv_dev(h, hPar, WHl, WLl, Bb, N, offL, offC, lbits, blockIdx.x,
           haloH, haloL, hkey, threadIdx.x);
}

// ---------- emb tile (verified; used by tail epilogue) ----------
__device__ __forceinline__ void emb_tile(float* __restrict__ h,
    const unsigned short* __restrict__ EH, const unsigned short* __restrict__ ELo,
    const float* __restrict__ embB, const float* __restrict__ lng,
    const float* __restrict__ lnb, const float* __restrict__ gain,
    int d, size_t rowbase, int validN, int lane){
  int q = lane >> 4, li = lane & 15;
  const float* rp = h + (rowbase + li)*64 + q*8;
  float4 a0 = *(const float4*)rp;
  float4 a1 = *(const float4*)(rp + 4);
  float4 a2 = *(const float4*)(rp + 32);
  float4 a3 = *(const float4*)(rp + 36);
  short8 ah0, al0, ah1, al1;
  split8(a0, a1, ah0, al0);
  split8(a2, a3, ah1, al1);
  f32x4 acc0 = {0.f,0.f,0.f,0.f}, acc1 = acc0, acc2 = acc0, acc3 = acc0;
  #define EMB_CB(CB, ACC) { \
    size_t f0 = (((size_t)(d*2+0)*4 + (CB))*64 + lane)*8; \
    size_t f1 = (((size_t)(d*2+1)*4 + (CB))*64 + lane)*8; \
    short8 bh0 = *(const short8*)(EH + f0); \
    short8 bl0 = *(const short8*)(ELo + f0); \
    short8 bh1 = *(const short8*)(EH + f1); \
    short8 bl1 = *(const short8*)(ELo + f1); \
    ACC = __builtin_amdgcn_mfma_f32_16x16x32_bf16(ah0, bh0, ACC, 0,0,0); \
    ACC = __builtin_amdgcn_mfma_f32_16x16x32_bf16(al0, bh0, ACC, 0,0,0); \
    ACC = __builtin_amdgcn_mfma_f32_16x16x32_bf16(ah0, bl0, ACC, 0,0,0); \
    ACC = __builtin_amdgcn_mfma_f32_16x16x32_bf16(ah1, bh1, ACC, 0,0,0); \
    ACC = __builtin_amdgcn_mfma_f32_16x16x32_bf16(al1, bh1, ACC, 0,0,0); \
    ACC = __builtin_amdgcn_mfma_f32_16x16x32_bf16(ah1, bl1, ACC, 0,0,0); }
  EMB_CB(0, acc0)
  EMB_CB(1, acc1)
  EMB_CB(2, acc2)
  EMB_CB(3, acc3)
  #undef EMB_CB
  float b0 = embB[d*64 +      li];
  float b1 = embB[d*64 + 16 + li];
  float b2 = embB[d*64 + 32 + li];
  float b3 = embB[d*64 + 48 + li];
  float mu[4], rs[4];
  float z0[4], z1[4], z2[4], z3[4];
  #pragma unroll
  for (int r=0;r<4;++r){
    z0[r] = acc0[r] + b0;
    z1[r] = acc1[r] + b1;
    z2[r] = acc2[r] + b2;
    z3[r] = acc3[r] + b3;
    float s  = z0[r] + z1[r] + z2[r] + z3[r];
    float qv = z0[r]*z0[r] + z1[r]*z1[r] + z2[r]*z2[r] + z3[r]*z3[r];
    #pragma unroll
    for (int mk=1; mk<16; mk<<=1){
      s  += __shfl_xor(s, mk, 64);
      qv += __shfl_xor(qv, mk, 64);
    }
    float m = s * 0.015625f;
    mu[r] = m;
    rs[r] = rsqrtf(qv * 0.015625f - m*m + 1e-5f);
  }
  float g0 = lng[d*64 +      li], l0 = lnb[d*64 +      li];
  float g1 = lng[d*64 + 16 + li], l1 = lnb[d*64 + 16 + li];
  float g2 = lng[d*64 + 32 + li], l2 = lnb[d*64 + 32 + li];
  float g3 = lng[d*64 + 48 + li], l3 = lnb[d*64 + 48 + li];
  float gn = gain[d];
  #pragma unroll
  for (int r=0;r<4;++r){
    int ni = q*4 + r;
    if (ni < validN){
      float* row = h + (rowbase + ni)*64;
      row[     li] = ((z0[r] - mu[r])*rs[r]*g0 + l0)*gn;
      row[16 + li] = ((z1[r] - mu[r])*rs[r]*g1 + l1)*gn;
      row[32 + li] = ((z2[r] - mu[r])*rs[r]*g2 + l2)*gn;
      row[48 + li] = ((z3[r] - mu[r])*rs[r]*g3 + l3)*gn;
    }
  }
}

// ---------- pipelined emb pair (verified) + nontemporal stores ----------
__device__ __forceinline__ void emb_pair(float* __restrict__ h,
    const unsigned short* __restrict__ EH, const unsigned short* __restrict__ ELo,
    const float* __restrict__ embB, const float* __restrict__ lng,
    const float* __restrict__ lnb, const float* __restrict__ gain,
    int d, size_t rb1, size_t rb2, int lane){
  int q = lane >> 4, li = lane & 15;
  const float* rp1 = h + (rb1 + li)*64 + q*8;
  const float* rp2 = h + (rb2 + li)*64 + q*8;
  float4 x0 = *(const float4*)rp1;
  float4 x1 = *(const float4*)(rp1 + 4);
  float4 x2 = *(const float4*)(rp1 + 32);
  float4 x3 = *(const float4*)(rp1 + 36);
  float4 y0 = *(const float4*)rp2;
  float4 y1 = *(const float4*)(rp2 + 4);
  float4 y2 = *(const float4*)(rp2 + 32);
  float4 y3 = *(const float4*)(rp2 + 36);
  short8 Xh0, Xl0, Xh1, Xl1, Yh0, Yl0, Yh1, Yl1;
  split8(x0, x1, Xh0, Xl0);
  split8(x2, x3, Xh1, Xl1);
  split8(y0, y1, Yh0, Yl0);
  split8(y2, y3, Yh1, Yl1);
  f32x4 pA0 = {0.f,0.f,0.f,0.f}, pA1 = pA0, pA2 = pA0, pA3 = pA0;
  f32x4 pB0 = pA0, pB1 = pA0, pB2 = pA0, pB3 = pA0;
  #define EMB_CB2(CB, ACCA, ACCB) { \
    size_t f0 = (((size_t)(d*2+0)*4 + (CB))*64 + lane)*8; \
    size_t f1 = (((size_t)(d*2+1)*4 + (CB))*64 + lane)*8; \
    short8 bh0 = *(const short8*)(EH + f0); \
    short8 bl0 = *(const short8*)(ELo + f0); \
    short8 bh1 = *(const short8*)(EH + f1); \
    short8 bl1 = *(const short8*)(ELo + f1); \
    ACCA = __builtin_amdgcn_mfma_f32_16x16x32_bf16(Xh0, bh0, ACCA, 0,0,0); \
    ACCB = __builtin_amdgcn_mfma_f32_16x16x32_bf16(Yh0, bh0, ACCB, 0,0,0); \
    ACCA = __builtin_amdgcn_mfma_f32_16x16x32_bf16(Xl0, bh0, ACCA, 0,0,0); \
    ACCB = __builtin_amdgcn_mfma_f32_16x16x32_bf16(Yl0, bh0, ACCB, 0,0,0); \
    ACCA = __builtin_amdgcn_mfma_f32_16x16x32_bf16(Xh0, bl0, ACCA, 0,0,0); \
    ACCB = __builtin_amdgcn_mfma_f32_16x16x32_bf16(Yh0, bl0, ACCB, 0,0,0); \
    ACCA = __builtin_amdgcn_mfma_f32_16x16x32_bf16(Xh1, bh1, ACCA, 0,0,0); \
    ACCB = __builtin_amdgcn_mfma_f32_16x16x32_bf16(Yh1, bh1, ACCB, 0,0,0); \
    ACCA = __builtin_amdgcn_mfma_f32_16x16x32_bf16(Xl1, bh1, ACCA, 0,0,0); \
    ACCB = __builtin_amdgcn_mfma_f32_16x16x32_bf16(Yl1, bh1, ACCB, 0,0,0); \
    ACCA = __builtin_amdgcn_mfma_f32_16x16x32_bf16(Xh1, bl1, ACCA, 0,0,0); \
    ACCB = __builtin_amdgcn_mfma_f32_16x16x32_bf16(Yh1, bl1, ACCB, 0,0,0); }
  EMB_CB2(0, pA0, pB0)
  EMB_CB2(1, pA1, pB1)
  EMB_CB2(2, pA2, pB2)
  EMB_CB2(3, pA3, pB3)
  #undef EMB_CB2
  float b0 = embB[d*64 +      li];
  float b1 = embB[d*64 + 16 + li];
  float b2 = embB[d*64 + 32 + li];
  float b3 = embB[d*64 + 48 + li];
  float g0 = lng[d*64 +      li], l0 = lnb[d*64 +      li];
  float g1 = lng[d*64 + 16 + li], l1 = lnb[d*64 + 16 + li];
  float g2 = lng[d*64 + 32 + li], l2 = lnb[d*64 + 32 + li];
  float g3 = lng[d*64 + 48 + li], l3 = lnb[d*64 + 48 + li];
  float gn = gain[d];
  #define EMB_FIN(ACC0, ACC1, ACC2, ACC3, RB) { \
    _Pragma("unroll") \
    for (int r=0;r<4;++r){ \
      float z0 = ACC0[r] + b0, z1 = ACC1[r] + b1; \
      float z2 = ACC2[r] + b2, z3 = ACC3[r] + b3; \
      float s  = z0 + z1 + z2 + z3; \
      float qv = z0*z0 + z1*z1 + z2*z2 + z3*z3; \
      _Pragma("unroll") \
      for (int mk=1; mk<16; mk<<=1){ \
        s  += __shfl_xor(s, mk, 64); \
        qv += __shfl_xor(qv, mk, 64); \
      } \
      float m = s * 0.015625f; \
      float rsv = rsqrtf(qv * 0.015625f - m*m + 1e-5f); \
      float* row = h + ((RB) + (size_t)(q*4 + r))*64; \
      __builtin_nontemporal_store(((z0 - m)*rsv*g0 + l0)*gn, row + li); \
      __builtin_nontemporal_store(((z1 - m)*rsv*g1 + l1)*gn, row + 16 + li); \
      __builtin_nontemporal_store(((z2 - m)*rsv*g2 + l2)*gn, row + 32 + li); \
      __builtin_nontemporal_store(((z3 - m)*rsv*g3 + l3)*gn, row + 48 + li); \
    } }
  EMB_FIN(pA0, pA1, pA2, pA3, rb1)
  EMB_FIN(pB0, pB1, pB2, pB3, rb2)
  #undef EMB_FIN
}

// ---------- tail level, 16-wave, depth-2 B-frag prefetch (round-21 verified) ----------
template<int L>
__device__ __forceinline__ void tail_level2(float* __restrict__ h,
    const unsigned short* __restrict__ WHc, const unsigned short* __restrict__ WLc,
    const float* __restrict__ convB, const float* __restrict__ Hpar,
    unsigned short* __restrict__ PtH, unsigned short* __restrict__ PtL, int t){
  constexpr int Np  = 1 << (2*L);
  constexpr int NTt = (Np + 15)/16;
  constexpr int TG  = (NTt + 3)/4;
  constexpr int res = 1 << L;
  int w  = t >> 6;
  int cb = __builtin_amdgcn_readfirstlane(w & 3);
  int tg = __builtin_amdgcn_readfirstlane(w >> 2);
  int lane = t & 63;
  int q = lane >> 4, li = lane & 15;
  int chl = cb*16 + li;
  int lx[TG], ly[TG];
  #pragma unroll
  for (int i=0;i<TG;++i){
    unsigned n = (unsigned)((tg*TG + i)*16 + li);
    lx[i] = (int)deint(n); ly[i] = (int)deint(n >> 1);
  }
  f32x4 acc[TG];
  #pragma unroll
  for (int i=0;i<TG;++i) acc[i] = f32x4{0.f,0.f,0.f,0.f};
  short8 Ah0, Al0, Ah1, Al1, Bh0, Bl0, Bh1, Bl1;
  #define TL_LOAD(MM, H0, L0, H1, L1) { \
    size_t f0 = ((size_t)(((MM)*2+0)*4 + cb)*64 + lane)*8; \
    size_t f1 = ((size_t)(((MM)*2+1)*4 + cb)*64 + lane)*8; \
    H0 = *(const short8*)(WHc + f0); L0 = *(const short8*)(WLc + f0); \
    H1 = *(const short8*)(WHc + f1); L1 = *(const short8*)(WLc + f1); }
  #define TL_COMP(MM, H0, L0, H1, L1) { \
    const int dy = (MM)/3 - 1, dx = (MM)%3 - 1; \
    _Pragma("unroll") \
    for (int i=0;i<TG;++i){ \
      int nx = lx[i]+dx, ny = ly[i]+dy; \
      int key = (nx>=0 && ny>=0 && nx<res && ny<res) \
              ? (int)(ileave((unsigned)nx) | (ileave((unsigned)ny)<<1)) : Np; \
      const unsigned short* pH = PtH + key*72; \
      const unsigned short* pL = PtL + key*72; \
      short8 ah0 = *(const short8*)(pH + q*8); \
      short8 al0 = *(const short8*)(pL + q*8); \
      short8 ah1 = *(const short8*)(pH + 32 + q*8); \
      short8 al1 = *(const short8*)(pL + 32 + q*8); \
      acc[i] = __builtin_amdgcn_mfma_f32_16x16x32_bf16(ah0, H0, acc[i], 0,0,0); \
      acc[i] = __builtin_amdgcn_mfma_f32_16x16x32_bf16(al0, H0, acc[i], 0,0,0); \
      acc[i] = __builtin_amdgcn_mfma_f32_16x16x32_bf16(ah0, L0, acc[i], 0,0,0); \
      acc[i] = __builtin_amdgcn_mfma_f32_16x16x32_bf16(ah1, H1, acc[i], 0,0,0); \
      acc[i] = __builtin_amdgcn_mfma_f32_16x16x32_bf16(al1, H1, acc[i], 0,0,0); \
      acc[i] = __builtin_amdgcn_mfma_f32_16x16x32_bf16(ah1, L1, acc[i], 0,0,0); \
    } }
  TL_LOAD(0, Ah0, Al0, Ah1, Al1)
  TL_LOAD(1, Bh0, Bl0, Bh1, Bl1)
  TL_COMP(0, Ah0, Al0, Ah1, Al1)  TL_LOAD(2, Ah0, Al0, Ah1, Al1)
  TL_COMP(1, Bh0, Bl0, Bh1, Bl1)  TL_LOAD(3, Bh0, Bl0, Bh1, Bl1)
  TL_COMP(2, Ah0, Al0, Ah1, Al1)  TL_LOAD(4, Ah0, Al0, Ah1, Al1)
  TL_COMP(3, Bh0, Bl0, Bh1, Bl1)  TL_LOAD(5, Bh0, Bl0, Bh1, Bl1)
  TL_COMP(4, Ah0, Al0, Ah1, Al1)  TL_LOAD(6, Ah0, Al0, Ah1, Al1)
  TL_COMP(5, Bh0, Bl0, Bh1, Bl1)  TL_LOAD(7, Bh0, Bl0, Bh1, Bl1)
  TL_COMP(6, Ah0, Al0, Ah1, Al1)  TL_LOAD(8, Ah0, Al0, Ah1, Al1)
  TL_COMP(7, Bh0, Bl0, Bh1, Bl1)
  TL_COMP(8, Ah0, Al0, Ah1, Al1)
  #undef TL_LOAD
  #undef TL_COMP
  float bias = convB[L*64 + chl];
  float vq[TG][4];
  #pragma unroll
  for (int i=0;i<TG;++i){
    #pragma unroll
    for (int reg=0;reg<4;++reg){
      int ni = (tg*TG + i)*16 + q*4 + reg;
      float v = acc[i][reg] + bias;
      v = v > 0.f ? v : 0.f;
      vq[i][reg] = v;
      if (ni < Np) h[(size_t)(OFFS[L] + ni)*64 + chl] = v;
    }
  }
  __syncthreads();
  if (L > 1){
    constexpr int Pp = Np/4;
    #pragma unroll
    for (int i=0;i<TG;++i){
      int p = (tg*TG + i)*4 + q;
      if (p < Pp){
        float pooled = 0.25f*(vq[i][0]+vq[i][1]+vq[i][2]+vq[i][3])
                     + Hpar[(size_t)(OFFS[L-1] + p)*64 + chl];
        unsigned short hh = f2bh(pooled);
        PtH[p*72 + chl] = hh;
        PtL[p*72 + chl] = f2bh(pooled - bh2f(hh));
      }
    }
    if (t < 64){ PtH[Pp*72 + t] = 0; PtL[Pp*72 + t] = 0; }
  } else {
    if (tg == 0 && q == 0){
      float pooled = 0.25f*(vq[0][0]+vq[0][1]+vq[0][2]+vq[0][3]) + Hpar[chl];
      h[chl] = pooled;
    }
  }
  __syncthreads();
}

// ---------- final launch (1024 thr): block 0 = tail + emb0..4; 1.. = emb1024 ----------
__global__ __launch_bounds__(1024) void k_final(float* __restrict__ h,
    const unsigned short* __restrict__ WH, const unsigned short* __restrict__ WLo,
    const float* __restrict__ convB,
    const unsigned short* __restrict__ EH, const unsigned short* __restrict__ ELo,
    const float* __restrict__ embB, const float* __restrict__ lng,
    const float* __restrict__ lnb, const float* __restrict__ gain){
  __shared__ __align__(16) char smem[24128];
  unsigned short* PtH = (unsigned short*)smem;               //  9360 B
  unsigned short* PtL = (unsigned short*)(smem + 9360);      //  9360 B
  float* Hpar = (float*)(smem + 18720);                      //  5376 B
  int t = threadIdx.x;
  int w = t >> 6, lane = t & 63;
  int b = blockIdx.x;
  if (b != 0){
    // emb levels 5..9 in 1024-node blocks: wave w covers tiles {w, w+16, w+32, w+48}
    int bb = b - 1;
    int d, blk;
    if      (bb < 256){ d = 9; blk = bb;       }
    else if (bb < 320){ d = 8; blk = bb - 256; }
    else if (bb < 336){ d = 7; blk = bb - 320; }
    else if (bb < 340){ d = 6; blk = bb - 336; }
    else              { d = 5; blk = bb - 340; }
    size_t base = (size_t)OFFS[d] + (size_t)blk*1024;
    emb_pair(h, EH, ELo, embB, lng, lnb, gain, d,
             base + (size_t)w*16, base + (size_t)(w+16)*16, lane);
    emb_pair(h, EH, ELo, embB, lng, lnb, gain, d,
             base + (size_t)(w+32)*16, base + (size_t)(w+48)*16, lane);
    return;
  }
  // ---- block 0: tail levels 3..1 + emb levels 0..4 ----
  for (int e = t; e < 21*16; e += 1024)
    ((float4*)Hpar)[e] = ((const float4*)h)[e];
  for (int e = t; e < 65*16; e += 1024){
    int node = e >> 4, u = e & 15;
    float4 r = make_float4(0.f,0.f,0.f,0.f);
    if (node < 64){
      const float4* c = (const float4*)(h + (size_t)(OFFS[4] + 4*node)*64) + u;
      float4 c0 = c[0], c1 = c[16], c2 = c[32], c3 = c[48];
      float4 pr = *((const float4*)(h + (size_t)(OFFS[3] + node)*64) + u);
      r.x = 0.25f*(c0.x+c1.x+c2.x+c3.x) + pr.x;
      r.y = 0.25f*(c0.y+c1.y+c2.y+c3.y) + pr.y;
      r.z = 0.25f*(c0.z+c1.z+c2.z+c3.z) + pr.z;
      r.w = 0.25f*(c0.w+c1.w+c2.w+c3.w) + pr.w;
    }
    unsigned short h0=f2bh(r.x), h1=f2bh(r.y), h2=f2bh(r.z), h3=f2bh(r.w);
    *(ushort4*)&PtH[node*72 + u*4] = make_ushort4(h0,h1,h2,h3);
    *(ushort4*)&PtL[node*72 + u*4] = make_ushort4(
        f2bh(r.x - bh2f(h0)), f2bh(r.y - bh2f(h1)),
        f2bh(r.z - bh2f(h2)), f2bh(r.w - bh2f(h3)));
  }
  __syncthreads();
  tail_level2<3>(h, WH + (size_t)2*36864, WLo + (size_t)2*36864, convB, Hpar, PtH, PtL, t);
  tail_level2<2>(h, WH + (size_t)1*36864, WLo + (size_t)1*36864, convB, Hpar, PtH, PtL, t);
  tail_level2<1>(h, WH,                   WLo,                   convB, Hpar, PtH, PtL, t);
  // epilogue: emb levels 0..4 (23 tile-jobs over 16 waves)
  for (int j = w; j < 23; j += 16){
    int d, tile;
    if (j < 16)      { d=4; tile=j;    }
    else if (j < 20) { d=3; tile=j-16; }
    else if (j == 20){ d=2; tile=0;    }
    else if (j == 21){ d=1; tile=0;    }
    else             { d=0; tile=0;    }
    int Nlev = 1 << (2*d);
    int valid = Nlev - tile*16;
    emb_tile(h, EH, ELo, embB, lng, lnb, gain, d,
             (size_t)OFFS[d] + (size_t)tile*16, valid > 16 ? 16 : valid, lane);
  }
}

extern "C" void kernel_launch(void* const* d_in, const int* in_sizes, int n_in,
                              void* d_out, int out_size, void* d_ws, size_t ws_size,
                              hipStream_t stream) {
  (void)in_sizes; (void)n_in; (void)out_size;
  const float* feat  = (const float*)d_in[0];
  const float* ipW   = (const float*)d_in[1];
  const float* ipB   = (const float*)d_in[2];
  const float* convW = (const float*)d_in[3];
  const float* convB = (const float*)d_in[4];
  const float* embW  = (const float*)d_in[5];
  const float* embB  = (const float*)d_in[6];
  const float* lng   = (const float*)d_in[7];
  const float* lnb   = (const float*)d_in[8];
  const float* gain  = (const float*)d_in[9];
  float* h = (float*)d_out;

  unsigned short* WH  = (unsigned short*)d_ws;
  unsigned short* WLo = WH + FRAG_USH;
  const unsigned short* EH  = WH  + CONV_USH;
  const unsigned short* ELo = WLo + CONV_USH;
  float* hpre = (ws_size >= FRAG_BYTES + HPRE_BYTES)
              ? (float*)((char*)d_ws + FRAG_BYTES) : nullptr;

  // 1: merged W-prep + inproj
  k_prep<<<WPREP_BLOCKS + INPROJ_BLOCKS, 256, 0, stream>>>(
      convW, embW, WH, WLo, feat, ipW, ipB, h, hpre);

  // 2..6: bare conv L=8..4
  for (int L = 8; L >= 4; --L){
    int Np = 1 << (2*L);
    const float* hPar = hpre ? (hpre + (size_t)(OFFS[L] - OFFS[4])*64)
                             : (h + (size_t)OFFS[L]*64);
    k_conv<<<Np/64, 256, 0, stream>>>(h, hPar,
        WH  + (size_t)(L-1)*36864, WLo + (size_t)(L-1)*36864,
        convB + (size_t)L*64, Np, OFFS[L], OFFS[L+1], L);
  }

  // 7: final — 16-wave tail + all emb (levels 5..9, 1024-node blocks, 2 pairs/wave)
  k_final<<<1 + 341, 1024, 0, stream>>>(h, WH, WLo, convB,
      EH, ELo, embB, lng, lnb, gain);
}

// Round 23
// 204.102 us; speedup vs baseline: 1.0123x; 1.0123x over previous
//
#include <hip/hip_runtime.h>
#include <hip/hip_bf16.h>

static constexpr int TOTAL = 349525;
static constexpr int OFFS[11] = {0,1,5,21,85,341,1365,5461,21845,87381,349525};
static constexpr size_t CONV_USH = (size_t)8*9*2*4*64*8;    // 294912 ushorts
static constexpr size_t EMB_USH  = (size_t)10*2*4*64*8;     //  40960 ushorts
static constexpr size_t FRAG_USH = CONV_USH + EMB_USH;      // 335872
static constexpr size_t FRAG_BYTES = FRAG_USH*2*2;          // 1343488 B
static constexpr size_t HPRE_BYTES = (size_t)(87381-85)*64*4;
static constexpr int WPREP_BLOCKS = 164;
static constexpr int INPROJ_BLOCKS = (TOTAL + 127)/128;     // 2731

typedef __attribute__((ext_vector_type(8))) short short8;
typedef __attribute__((ext_vector_type(4))) float f32x4;

__device__ __forceinline__ unsigned deint(unsigned v){
  v &= 0x55555555u;
  v = (v | (v>>1)) & 0x33333333u;
  v = (v | (v>>2)) & 0x0F0F0F0Fu;
  v = (v | (v>>4)) & 0x00FF00FFu;
  v = (v | (v>>8)) & 0x0000FFFFu;
  return v;
}
__device__ __forceinline__ unsigned ileave(unsigned v){
  v &= 0xFFFFu;
  v = (v | (v<<8)) & 0x00FF00FFu;
  v = (v | (v<<4)) & 0x0F0F0F0Fu;
  v = (v | (v<<2)) & 0x33333333u;
  v = (v | (v<<1)) & 0x55555555u;
  return v;
}
__device__ __forceinline__ unsigned short f2bh(float x){
  unsigned u = __float_as_uint(x);
  return (unsigned short)((u + 0x7FFFu + ((u>>16)&1u)) >> 16);
}
__device__ __forceinline__ float bh2f(unsigned short h){
  return __uint_as_float(((unsigned)h) << 16);
}
__device__ __forceinline__ void split8(float4 a, float4 b, short8 &hi, short8 &lo){
  float v[8] = {a.x,a.y,a.z,a.w,b.x,b.y,b.z,b.w};
  unsigned short hv[8], lv[8];
  #pragma unroll
  for (int j=0;j<8;++j){ hv[j]=f2bh(v[j]); lv[j]=f2bh(v[j]-bh2f(hv[j])); }
  hi = short8{(short)hv[0],(short)hv[1],(short)hv[2],(short)hv[3],
              (short)hv[4],(short)hv[5],(short)hv[6],(short)hv[7]};
  lo = short8{(short)lv[0],(short)lv[1],(short)lv[2],(short)lv[3],
              (short)lv[4],(short)lv[5],(short)lv[6],(short)lv[7]};
}

// ---------- merged prep: blocks <164 = W-frag prep; rest = inproj (verified) ----------
__global__ __launch_bounds__(256) void k_prep(const float* __restrict__ convW,
    const float* __restrict__ embW,
    unsigned short* __restrict__ WH, unsigned short* __restrict__ WLo,
    const float* __restrict__ feat, const float* __restrict__ ipW,
    const float* __restrict__ ipB, float* __restrict__ h,
    float* __restrict__ hpre){
  __shared__ float Alt[128][44];
  __shared__ float Wl[40][68];
  int t = threadIdx.x;
  if ((int)blockIdx.x < WPREP_BLOCKS){
    int tid = blockIdx.x*256 + t;
    if (tid >= 41984) return;
    const float* src;
    size_t dst;
    if (tid < 36864){
      int l=tid&63, cb=(tid>>6)&3, ks=(tid>>8)&1;
      int x=tid>>9; int m=x%9, Lp=x/9;
      int k0=ks*32+((l>>4)<<3), ch=cb*16+(l&15);
      src = convW + (size_t)(Lp+1)*36864 + (size_t)(m*64+k0)*64 + ch;
      dst = (size_t)tid*8;
    } else {
      int t2 = tid - 36864;
      int l=t2&63, cb=(t2>>6)&3, ks=(t2>>8)&1, d=t2>>9;
      int k0=ks*32+((l>>4)<<3), ch=cb*16+(l&15);
      src = embW + (size_t)d*4096 + (size_t)k0*64 + ch;
      dst = CONV_USH + (size_t)t2*8;
    }
    unsigned short hv[8], lv[8];
    #pragma unroll
    for (int j=0;j<8;++j){
      float v = src[(size_t)j*64];
      unsigned short hh = f2bh(v);
      hv[j] = hh;
      lv[j] = f2bh(v - bh2f(hh));
    }
    short8 vh = {(short)hv[0],(short)hv[1],(short)hv[2],(short)hv[3],
                 (short)hv[4],(short)hv[5],(short)hv[6],(short)hv[7]};
    short8 vl = {(short)lv[0],(short)lv[1],(short)lv[2],(short)lv[3],
                 (short)lv[4],(short)lv[5],(short)lv[6],(short)lv[7]};
    *(short8*)(WH  + dst) = vh;
    *(short8*)(WLo + dst) = vl;
    return;
  }
  int base = ((int)blockIdx.x - WPREP_BLOCKS) * 128;
  for (int idx = t; idx < 40*64; idx += 256)
    Wl[idx >> 6][idx & 63] = ipW[idx];
  if (t < 128){
    int g = base + t;
    float* row = Alt[t];
    if (g < TOTAL){
      int d = 0;
      #pragma unroll
      for (int i = 1; i <= 9; ++i) if (g >= OFFS[i]) d = i;
      int local = g - OFFS[d];
      unsigned ix = deint((unsigned)local), iy = deint(((unsigned)local) >> 1);
      float inv = 1.0f / (float)(1 << d);
      float px = ((float)ix + 0.5f) * inv;
      float py = ((float)iy + 0.5f) * inv;
      float pd = (float)d * (1.0f/9.0f);
      row[0] = feat[g]; row[1] = px; row[2] = py; row[3] = pd;
      float p3[3] = {px, py, pd};
      #pragma unroll
      for (int c = 0; c < 3; ++c){
        float s, co;
        __sincosf(6.28318530717958647692f * p3[c], &s, &co);
        float* rb = row + 4 + c*12;
        #pragma unroll
        for (int f = 0; f < 6; ++f){
          rb[f] = s; rb[6+f] = co;
          float s2 = 2.f*s*co, c2 = 1.f - 2.f*s*s;
          s = s2; co = c2;
        }
      }
    } else {
      #pragma unroll
      for (int k = 0; k < 40; ++k) row[k] = 0.f;
    }
  }
  __syncthreads();
  int tr = t >> 3, tc = t & 7;
  float acc[4][8];
  #pragma unroll
  for (int i=0;i<4;++i)
    #pragma unroll
    for (int c=0;c<8;++c) acc[i][c] = 0.f;
  #pragma unroll 2
  for (int k4 = 0; k4 < 10; ++k4){
    float av4[4][4];
    #pragma unroll
    for (int i=0;i<4;++i){
      float4 aa = *(const float4*)&Alt[tr*4+i][k4*4];
      av4[i][0]=aa.x; av4[i][1]=aa.y; av4[i][2]=aa.z; av4[i][3]=aa.w;
    }
    #pragma unroll
    for (int j=0;j<4;++j){
      float4 lo = *(const float4*)&Wl[k4*4+j][tc*8];
      float4 hi = *(const float4*)&Wl[k4*4+j][tc*8+4];
      float wv[8];
      wv[0]=lo.x; wv[1]=lo.y; wv[2]=lo.z; wv[3]=lo.w;
      wv[4]=hi.x; wv[5]=hi.y; wv[6]=hi.z; wv[7]=hi.w;
      #pragma unroll
      for (int i=0;i<4;++i){
        float a = av4[i][j];
        #pragma unroll
        for (int c=0;c<8;++c) acc[i][c] += a*wv[c];
      }
    }
  }
  #pragma unroll
  for (int i=0;i<4;++i){
    int g = base + tr*4 + i;
    if (g >= TOTAL) continue;
    float ov[8];
    #pragma unroll
    for (int c=0;c<8;++c) ov[c] = acc[i][c] + ipB[tc*8+c];
    float* dst = &h[(size_t)g*64 + tc*8];
    *(float4*)dst       = *(const float4*)&ov[0];
    *(float4*)(dst + 4) = *(const float4*)&ov[4];
    if (hpre && g >= OFFS[4] && g < OFFS[9]){
      float* dp = hpre + (size_t)(g - OFFS[4])*64 + tc*8;
      *(float4*)dp       = *(const float4*)&ov[0];
      *(float4*)(dp + 4) = *(const float4*)&ov[4];
    }
  }
}

// ---------- conv body (verified): halo + fused pool + MFMA bf16-split ----------
__device__ __forceinline__ void conv_dev(float* __restrict__ h,
    const float* __restrict__ hPar,
    const unsigned short* __restrict__ WHl, const unsigned short* __restrict__ WLl,
    const float* __restrict__ Bb, int N, int offL, int offC, int lbits, int bnum,
    unsigned short* haloH, unsigned short* haloL, int* hkey, int t){
  int nb = bnum * 64;
  int res = 1 << lbits;
  if (t < 100){
    int i = t % 10, j = t / 10;
    int gx = (int)deint((unsigned)nb) - 1 + i;
    int gy = (int)deint(((unsigned)nb)>>1) - 1 + j;
    bool ok = (gx>=0 && gy>=0 && gx<res && gy<res);
    hkey[t] = ok ? (int)(ileave((unsigned)gx) | (ileave((unsigned)gy)<<1)) : -1;
  }
  __syncthreads();
  const float* hC = h + (size_t)offC*64;
  for (int e = t; e < 1600; e += 256){
    int hi_ = e >> 4, u = e & 15;
    int key = hkey[hi_];
    float4 r = make_float4(0.f,0.f,0.f,0.f);
    if (key >= 0){
      const float4* c = (const float4*)(hC + (size_t)(4*key)*64) + u;
      float4 c0 = c[0], c1 = c[16], c2 = c[32], c3 = c[48];
      float4 pr = *((const float4*)(hPar + (size_t)key*64) + u);
      r.x = 0.25f*(c0.x+c1.x+c2.x+c3.x) + pr.x;
      r.y = 0.25f*(c0.y+c1.y+c2.y+c3.y) + pr.y;
      r.z = 0.25f*(c0.z+c1.z+c2.z+c3.z) + pr.z;
      r.w = 0.25f*(c0.w+c1.w+c2.w+c3.w) + pr.w;
    }
    unsigned short h0=f2bh(r.x), h1=f2bh(r.y), h2=f2bh(r.z), h3=f2bh(r.w);
    *(ushort4*)&haloH[hi_*72 + u*4] = make_ushort4(h0,h1,h2,h3);
    *(ushort4*)&haloL[hi_*72 + u*4] = make_ushort4(
        f2bh(r.x - bh2f(h0)), f2bh(r.y - bh2f(h1)),
        f2bh(r.z - bh2f(h2)), f2bh(r.w - bh2f(h3)));
  }
  __syncthreads();
  int cb   = __builtin_amdgcn_readfirstlane(t >> 6);
  int lane = t & 63;
  int q = lane >> 4;
  int chl = cb*16 + (lane & 15);
  int lx0,ly0,lx1,ly1,lx2,ly2,lx3,ly3;
  {
    int n0 = (lane&15), n1 = 16+(lane&15), n2 = 32+(lane&15), n3 = 48+(lane&15);
    lx0=(int)deint((unsigned)n0); ly0=(int)deint(((unsigned)n0)>>1);
    lx1=(int)deint((unsigned)n1); ly1=(int)deint(((unsigned)n1)>>1);
    lx2=(int)deint((unsigned)n2); ly2=(int)deint(((unsigned)n2)>>1);
    lx3=(int)deint((unsigned)n3); ly3=(int)deint(((unsigned)n3)>>1);
  }
  f32x4 acc0 = {0.f,0.f,0.f,0.f}, acc1 = acc0, acc2 = acc0, acc3 = acc0;
  #pragma unroll 1
  for (int dy=0;dy<3;++dy){
    #pragma unroll 1
    for (int dx=0;dx<3;++dx){
      int m = dy*3 + dx;
      int r0 = (ly0+dy)*10 + lx0+dx;
      int r1 = (ly1+dy)*10 + lx1+dx;
      int r2 = (ly2+dy)*10 + lx2+dx;
      int r3 = (ly3+dy)*10 + lx3+dx;
      #pragma unroll
      for (int ks=0;ks<2;++ks){
        const unsigned short* fp = WHl + ((size_t)((m*2+ks)*4 + cb)*64 + lane)*8;
        const unsigned short* fq = WLl + ((size_t)((m*2+ks)*4 + cb)*64 + lane)*8;
        short8 bh = *(const short8*)fp;
        short8 bl = *(const short8*)fq;
        int so = (ks*4 + q)*8;
        short8 ah0 = *(const short8*)&haloH[r0*72 + so];
        short8 al0 = *(const short8*)&haloL[r0*72 + so];
        short8 ah1 = *(const short8*)&haloH[r1*72 + so];
        short8 al1 = *(const short8*)&haloL[r1*72 + so];
        short8 ah2 = *(const short8*)&haloH[r2*72 + so];
        short8 al2 = *(const short8*)&haloL[r2*72 + so];
        short8 ah3 = *(const short8*)&haloH[r3*72 + so];
        short8 al3 = *(const short8*)&haloL[r3*72 + so];
        acc0 = __builtin_amdgcn_mfma_f32_16x16x32_bf16(ah0, bh, acc0, 0,0,0);
        acc1 = __builtin_amdgcn_mfma_f32_16x16x32_bf16(ah1, bh, acc1, 0,0,0);
        acc2 = __builtin_amdgcn_mfma_f32_16x16x32_bf16(ah2, bh, acc2, 0,0,0);
        acc3 = __builtin_amdgcn_mfma_f32_16x16x32_bf16(ah3, bh, acc3, 0,0,0);
        acc0 = __builtin_amdgcn_mfma_f32_16x16x32_bf16(al0, bh, acc0, 0,0,0);
        acc1 = __builtin_amdgcn_mfma_f32_16x16x32_bf16(al1, bh, acc1, 0,0,0);
        acc2 = __builtin_amdgcn_mfma_f32_16x16x32_bf16(al2, bh, acc2, 0,0,0);
        acc3 = __builtin_amdgcn_mfma_f32_16x16x32_bf16(al3, bh, acc3, 0,0,0);
        acc0 = __builtin_amdgcn_mfma_f32_16x16x32_bf16(ah0, bl, acc0, 0,0,0);
        acc1 = __builtin_amdgcn_mfma_f32_16x16x32_bf16(ah1, bl, acc1, 0,0,0);
        acc2 = __builtin_amdgcn_mfma_f32_16x16x32_bf16(ah2, bl, acc2, 0,0,0);
        acc3 = __builtin_amdgcn_mfma_f32_16x16x32_bf16(ah3, bl, acc3, 0,0,0);
      }
    }
  }
  float bias = Bb[chl];
  int rowb = q*4;
  float* hO = h + (size_t)(offL + nb)*64;
  #pragma unroll
  for (int reg=0;reg<4;++reg){
    int n0 = rowb + reg;
    float v0 = acc0[reg] + bias; if (nb + n0      < N) hO[(size_t)(n0     )*64 + chl] = v0 > 0.f ? v0 : 0.f;
    float v1 = acc1[reg] + bias; if (nb + n0 + 16 < N) hO[(size_t)(n0 + 16)*64 + chl] = v1 > 0.f ? v1 : 0.f;
    float v2 = acc2[reg] + bias; if (nb + n0 + 32 < N) hO[(size_t)(n0 + 32)*64 + chl] = v2 > 0.f ? v2 : 0.f;
    float v3 = acc3[reg] + bias; if (nb + n0 + 48 < N) hO[(size_t)(n0 + 48)*64 + chl] = v3 > 0.f ? v3 : 0.f;
  }
}

// ---------- conv launch (bare) ----------
__global__ __launch_bounds__(256) void k_conv(float* __restrict__ h,
    const float* __restrict__ hPar,
    const unsigned short* __restrict__ WHl, const unsigned short* __restrict__ WLl,
    const float* __restrict__ Bb, int N, int offL, int offC, int lbits){
  __shared__ unsigned short haloH[100*72];
  __shared__ unsigned short haloL[100*72];
  __shared__ int hkey[100];
  conv_dev(h, hPar, WHl, WLl, Bb, N, offL, offC, lbits, blockIdx.x,
           haloH, haloL, hkey, threadIdx.x);
}

// ---------- emb tile (verified; used by tail epilogue) ----------
__device__ __forceinline__ void emb_tile(float* __restrict__ h,
    const unsigned short* __restrict__ EH, const unsigned short* __restrict__ ELo,
    const float* __restrict__ embB, const float* __restrict__ lng,
    const float* __restrict__ lnb, const float* __restrict__ gain,
    int d, size_t rowbase, int validN, int lane){
  int q = lane >> 4, li = lane & 15;
  const float* rp = h + (rowbase + li)*64 + q*8;
  float4 a0 = *(const float4*)rp;
  float4 a1 = *(const float4*)(rp + 4);
  float4 a2 = *(const float4*)(rp + 32);
  float4 a3 = *(const float4*)(rp + 36);
  short8 ah0, al0, ah1, al1;
  split8(a0, a1, ah0, al0);
  split8(a2, a3, ah1, al1);
  f32x4 acc0 = {0.f,0.f,0.f,0.f}, acc1 = acc0, acc2 = acc0, acc3 = acc0;
  #define EMB_CB(CB, ACC) { \
    size_t f0 = (((size_t)(d*2+0)*4 + (CB))*64 + lane)*8; \
    size_t f1 = (((size_t)(d*2+1)*4 + (CB))*64 + lane)*8; \
    short8 bh0 = *(const short8*)(EH + f0); \
    short8 bl0 = *(const short8*)(ELo + f0); \
    short8 bh1 = *(const short8*)(EH + f1); \
    short8 bl1 = *(const short8*)(ELo + f1); \
    ACC = __builtin_amdgcn_mfma_f32_16x16x32_bf16(ah0, bh0, ACC, 0,0,0); \
    ACC = __builtin_amdgcn_mfma_f32_16x16x32_bf16(al0, bh0, ACC, 0,0,0); \
    ACC = __builtin_amdgcn_mfma_f32_16x16x32_bf16(ah0, bl0, ACC, 0,0,0); \
    ACC = __builtin_amdgcn_mfma_f32_16x16x32_bf16(ah1, bh1, ACC, 0,0,0); \
    ACC = __builtin_amdgcn_mfma_f32_16x16x32_bf16(al1, bh1, ACC, 0,0,0); \
    ACC = __builtin_amdgcn_mfma_f32_16x16x32_bf16(ah1, bl1, ACC, 0,0,0); }
  EMB_CB(0, acc0)
  EMB_CB(1, acc1)
  EMB_CB(2, acc2)
  EMB_CB(3, acc3)
  #undef EMB_CB
  float b0 = embB[d*64 +      li];
  float b1 = embB[d*64 + 16 + li];
  float b2 = embB[d*64 + 32 + li];
  float b3 = embB[d*64 + 48 + li];
  float mu[4], rs[4];
  float z0[4], z1[4], z2[4], z3[4];
  #pragma unroll
  for (int r=0;r<4;++r){
    z0[r] = acc0[r] + b0;
    z1[r] = acc1[r] + b1;
    z2[r] = acc2[r] + b2;
    z3[r] = acc3[r] + b3;
    float s  = z0[r] + z1[r] + z2[r] + z3[r];
    float qv = z0[r]*z0[r] + z1[r]*z1[r] + z2[r]*z2[r] + z3[r]*z3[r];
    #pragma unroll
    for (int mk=1; mk<16; mk<<=1){
      s  += __shfl_xor(s, mk, 64);
      qv += __shfl_xor(qv, mk, 64);
    }
    float m = s * 0.015625f;
    mu[r] = m;
    rs[r] = rsqrtf(qv * 0.015625f - m*m + 1e-5f);
  }
  float g0 = lng[d*64 +      li], l0 = lnb[d*64 +      li];
  float g1 = lng[d*64 + 16 + li], l1 = lnb[d*64 + 16 + li];
  float g2 = lng[d*64 + 32 + li], l2 = lnb[d*64 + 32 + li];
  float g3 = lng[d*64 + 48 + li], l3 = lnb[d*64 + 48 + li];
  float gn = gain[d];
  #pragma unroll
  for (int r=0;r<4;++r){
    int ni = q*4 + r;
    if (ni < validN){
      float* row = h + (rowbase + ni)*64;
      row[     li] = ((z0[r] - mu[r])*rs[r]*g0 + l0)*gn;
      row[16 + li] = ((z1[r] - mu[r])*rs[r]*g1 + l1)*gn;
      row[32 + li] = ((z2[r] - mu[r])*rs[r]*g2 + l2)*gn;
      row[48 + li] = ((z3[r] - mu[r])*rs[r]*g3 + l3)*gn;
    }
  }
}

// ---------- pipelined emb pair (verified round 19/21: REGULAR stores) ----------
__device__ __forceinline__ void emb_pair(float* __restrict__ h,
    const unsigned short* __restrict__ EH, const unsigned short* __restrict__ ELo,
    const float* __restrict__ embB, const float* __restrict__ lng,
    const float* __restrict__ lnb, const float* __restrict__ gain,
    int d, size_t rb1, size_t rb2, int lane){
  int q = lane >> 4, li = lane & 15;
  const float* rp1 = h + (rb1 + li)*64 + q*8;
  const float* rp2 = h + (rb2 + li)*64 + q*8;
  float4 x0 = *(const float4*)rp1;
  float4 x1 = *(const float4*)(rp1 + 4);
  float4 x2 = *(const float4*)(rp1 + 32);
  float4 x3 = *(const float4*)(rp1 + 36);
  float4 y0 = *(const float4*)rp2;
  float4 y1 = *(const float4*)(rp2 + 4);
  float4 y2 = *(const float4*)(rp2 + 32);
  float4 y3 = *(const float4*)(rp2 + 36);
  short8 Xh0, Xl0, Xh1, Xl1, Yh0, Yl0, Yh1, Yl1;
  split8(x0, x1, Xh0, Xl0);
  split8(x2, x3, Xh1, Xl1);
  split8(y0, y1, Yh0, Yl0);
  split8(y2, y3, Yh1, Yl1);
  f32x4 pA0 = {0.f,0.f,0.f,0.f}, pA1 = pA0, pA2 = pA0, pA3 = pA0;
  f32x4 pB0 = pA0, pB1 = pA0, pB2 = pA0, pB3 = pA0;
  #define EMB_CB2(CB, ACCA, ACCB) { \
    size_t f0 = (((size_t)(d*2+0)*4 + (CB))*64 + lane)*8; \
    size_t f1 = (((size_t)(d*2+1)*4 + (CB))*64 + lane)*8; \
    short8 bh0 = *(const short8*)(EH + f0); \
    short8 bl0 = *(const short8*)(ELo + f0); \
    short8 bh1 = *(const short8*)(EH + f1); \
    short8 bl1 = *(const short8*)(ELo + f1); \
    ACCA = __builtin_amdgcn_mfma_f32_16x16x32_bf16(Xh0, bh0, ACCA, 0,0,0); \
    ACCB = __builtin_amdgcn_mfma_f32_16x16x32_bf16(Yh0, bh0, ACCB, 0,0,0); \
    ACCA = __builtin_amdgcn_mfma_f32_16x16x32_bf16(Xl0, bh0, ACCA, 0,0,0); \
    ACCB = __builtin_amdgcn_mfma_f32_16x16x32_bf16(Yl0, bh0, ACCB, 0,0,0); \
    ACCA = __builtin_amdgcn_mfma_f32_16x16x32_bf16(Xh0, bl0, ACCA, 0,0,0); \
    ACCB = __builtin_amdgcn_mfma_f32_16x16x32_bf16(Yh0, bl0, ACCB, 0,0,0); \
    ACCA = __builtin_amdgcn_mfma_f32_16x16x32_bf16(Xh1, bh1, ACCA, 0,0,0); \
    ACCB = __builtin_amdgcn_mfma_f32_16x16x32_bf16(Yh1, bh1, ACCB, 0,0,0); \
    ACCA = __builtin_amdgcn_mfma_f32_16x16x32_bf16(Xl1, bh1, ACCA, 0,0,0); \
    ACCB = __builtin_amdgcn_mfma_f32_16x16x32_bf16(Yl1, bh1, ACCB, 0,0,0); \
    ACCA = __builtin_amdgcn_mfma_f32_16x16x32_bf16(Xh1, bl1, ACCA, 0,0,0); \
    ACCB = __builtin_amdgcn_mfma_f32_16x16x32_bf16(Yh1, bl1, ACCB, 0,0,0); }
  EMB_CB2(0, pA0, pB0)
  EMB_CB2(1, pA1, pB1)
  EMB_CB2(2, pA2, pB2)
  EMB_CB2(3, pA3, pB3)
  #undef EMB_CB2
  float b0 = embB[d*64 +      li];
  float b1 = embB[d*64 + 16 + li];
  float b2 = embB[d*64 + 32 + li];
  float b3 = embB[d*64 + 48 + li];
  float g0 = lng[d*64 +      li], l0 = lnb[d*64 +      li];
  float g1 = lng[d*64 + 16 + li], l1 = lnb[d*64 + 16 + li];
  float g2 = lng[d*64 + 32 + li], l2 = lnb[d*64 + 32 + li];
  float g3 = lng[d*64 + 48 + li], l3 = lnb[d*64 + 48 + li];
  float gn = gain[d];
  #define EMB_FIN(ACC0, ACC1, ACC2, ACC3, RB) { \
    _Pragma("unroll") \
    for (int r=0;r<4;++r){ \
      float z0 = ACC0[r] + b0, z1 = ACC1[r] + b1; \
      float z2 = ACC2[r] + b2, z3 = ACC3[r] + b3; \
      float s  = z0 + z1 + z2 + z3; \
      float qv = z0*z0 + z1*z1 + z2*z2 + z3*z3; \
      _Pragma("unroll") \
      for (int mk=1; mk<16; mk<<=1){ \
        s  += __shfl_xor(s, mk, 64); \
        qv += __shfl_xor(qv, mk, 64); \
      } \
      float m = s * 0.015625f; \
      float rsv = rsqrtf(qv * 0.015625f - m*m + 1e-5f); \
      float* row = h + ((RB) + (size_t)(q*4 + r))*64; \
      row[     li] = ((z0 - m)*rsv*g0 + l0)*gn; \
      row[16 + li] = ((z1 - m)*rsv*g1 + l1)*gn; \
      row[32 + li] = ((z2 - m)*rsv*g2 + l2)*gn; \
      row[48 + li] = ((z3 - m)*rsv*g3 + l3)*gn; \
    } }
  EMB_FIN(pA0, pA1, pA2, pA3, rb1)
  EMB_FIN(pB0, pB1, pB2, pB3, rb2)
  #undef EMB_FIN
}

// ---------- tail level, 16-wave, depth-2 B-frag prefetch (round-21 verified) ----------
template<int L>
__device__ __forceinline__ void tail_level2(float* __restrict__ h,
    const unsigned short* __restrict__ WHc, const unsigned short* __restrict__ WLc,
    const float* __restrict__ convB, const float* __restrict__ Hpar,
    unsigned short* __restrict__ PtH, unsigned short* __restrict__ PtL, int t){
  constexpr int Np  = 1 << (2*L);
  constexpr int NTt = (Np + 15)/16;
  constexpr int TG  = (NTt + 3)/4;
  constexpr int res = 1 << L;
  int w  = t >> 6;
  int cb = __builtin_amdgcn_readfirstlane(w & 3);
  int tg = __builtin_amdgcn_readfirstlane(w >> 2);
  int lane = t & 63;
  int q = lane >> 4, li = lane & 15;
  int chl = cb*16 + li;
  int lx[TG], ly[TG];
  #pragma unroll
  for (int i=0;i<TG;++i){
    unsigned n = (unsigned)((tg*TG + i)*16 + li);
    lx[i] = (int)deint(n); ly[i] = (int)deint(n >> 1);
  }
  f32x4 acc[TG];
  #pragma unroll
  for (int i=0;i<TG;++i) acc[i] = f32x4{0.f,0.f,0.f,0.f};
  short8 Ah0, Al0, Ah1, Al1, Bh0, Bl0, Bh1, Bl1;
  #define TL_LOAD(MM, H0, L0, H1, L1) { \
    size_t f0 = ((size_t)(((MM)*2+0)*4 + cb)*64 + lane)*8; \
    size_t f1 = ((size_t)(((MM)*2+1)*4 + cb)*64 + lane)*8; \
    H0 = *(const short8*)(WHc + f0); L0 = *(const short8*)(WLc + f0); \
    H1 = *(const short8*)(WHc + f1); L1 = *(const short8*)(WLc + f1); }
  #define TL_COMP(MM, H0, L0, H1, L1) { \
    const int dy = (MM)/3 - 1, dx = (MM)%3 - 1; \
    _Pragma("unroll") \
    for (int i=0;i<TG;++i){ \
      int nx = lx[i]+dx, ny = ly[i]+dy; \
      int key = (nx>=0 && ny>=0 && nx<res && ny<res) \
              ? (int)(ileave((unsigned)nx) | (ileave((unsigned)ny)<<1)) : Np; \
      const unsigned short* pH = PtH + key*72; \
      const unsigned short* pL = PtL + key*72; \
      short8 ah0 = *(const short8*)(pH + q*8); \
      short8 al0 = *(const short8*)(pL + q*8); \
      short8 ah1 = *(const short8*)(pH + 32 + q*8); \
      short8 al1 = *(const short8*)(pL + 32 + q*8); \
      acc[i] = __builtin_amdgcn_mfma_f32_16x16x32_bf16(ah0, H0, acc[i], 0,0,0); \
      acc[i] = __builtin_amdgcn_mfma_f32_16x16x32_bf16(al0, H0, acc[i], 0,0,0); \
      acc[i] = __builtin_amdgcn_mfma_f32_16x16x32_bf16(ah0, L0, acc[i], 0,0,0); \
      acc[i] = __builtin_amdgcn_mfma_f32_16x16x32_bf16(ah1, H1, acc[i], 0,0,0); \
      acc[i] = __builtin_amdgcn_mfma_f32_16x16x32_bf16(al1, H1, acc[i], 0,0,0); \
      acc[i] = __builtin_amdgcn_mfma_f32_16x16x32_bf16(ah1, L1, acc[i], 0,0,0); \
    } }
  TL_LOAD(0, Ah0, Al0, Ah1, Al1)
  TL_LOAD(1, Bh0, Bl0, Bh1, Bl1)
  TL_COMP(0, Ah0, Al0, Ah1, Al1)  TL_LOAD(2, Ah0, Al0, Ah1, Al1)
  TL_COMP(1, Bh0, Bl0, Bh1, Bl1)  TL_LOAD(3, Bh0, Bl0, Bh1, Bl1)
  TL_COMP(2, Ah0, Al0, Ah1, Al1)  TL_LOAD(4, Ah0, Al0, Ah1, Al1)
  TL_COMP(3, Bh0, Bl0, Bh1, Bl1)  TL_LOAD(5, Bh0, Bl0, Bh1, Bl1)
  TL_COMP(4, Ah0, Al0, Ah1, Al1)  TL_LOAD(6, Ah0, Al0, Ah1, Al1)
  TL_COMP(5, Bh0, Bl0, Bh1, Bl1)  TL_LOAD(7, Bh0, Bl0, Bh1, Bl1)
  TL_COMP(6, Ah0, Al0, Ah1, Al1)  TL_LOAD(8, Ah0, Al0, Ah1, Al1)
  TL_COMP(7, Bh0, Bl0, Bh1, Bl1)
  TL_COMP(8, Ah0, Al0, Ah1, Al1)
  #undef TL_LOAD
  #undef TL_COMP
  float bias = convB[L*64 + chl];
  float vq[TG][4];
  #pragma unroll
  for (int i=0;i<TG;++i){
    #pragma unroll
    for (int reg=0;reg<4;++reg){
      int ni = (tg*TG + i)*16 + q*4 + reg;
      float v = acc[i][reg] + bias;
      v = v > 0.f ? v : 0.f;
      vq[i][reg] = v;
      if (ni < Np) h[(size_t)(OFFS[L] + ni)*64 + chl] = v;
    }
  }
  __syncthreads();
  if (L > 1){
    constexpr int Pp = Np/4;
    #pragma unroll
    for (int i=0;i<TG;++i){
      int p = (tg*TG + i)*4 + q;
      if (p < Pp){
        float pooled = 0.25f*(vq[i][0]+vq[i][1]+vq[i][2]+vq[i][3])
                     + Hpar[(size_t)(OFFS[L-1] + p)*64 + chl];
        unsigned short hh = f2bh(pooled);
        PtH[p*72 + chl] = hh;
        PtL[p*72 + chl] = f2bh(pooled - bh2f(hh));
      }
    }
    if (t < 64){ PtH[Pp*72 + t] = 0; PtL[Pp*72 + t] = 0; }
  } else {
    if (tg == 0 && q == 0){
      float pooled = 0.25f*(vq[0][0]+vq[0][1]+vq[0][2]+vq[0][3]) + Hpar[chl];
      h[chl] = pooled;
    }
  }
  __syncthreads();
}

// ---------- final launch (1024 thr): block 0 = tail + emb0..4; 1.. = emb1024 ----------
__global__ __launch_bounds__(1024) void k_final(float* __restrict__ h,
    const unsigned short* __restrict__ WH, const unsigned short* __restrict__ WLo,
    const float* __restrict__ convB,
    const unsigned short* __restrict__ EH, const unsigned short* __restrict__ ELo,
    const float* __restrict__ embB, const float* __restrict__ lng,
    const float* __restrict__ lnb, const float* __restrict__ gain){
  __shared__ __align__(16) char smem[24128];
  unsigned short* PtH = (unsigned short*)smem;               //  9360 B
  unsigned short* PtL = (unsigned short*)(smem + 9360);      //  9360 B
  float* Hpar = (float*)(smem + 18720);                      //  5376 B
  int t = threadIdx.x;
  int w = t >> 6, lane = t & 63;
  int b = blockIdx.x;
  if (b != 0){
    // emb levels 5..9 in 1024-node blocks: wave w covers tiles {w, w+16, w+32, w+48}
    int bb = b - 1;
    int d, blk;
    if      (bb < 256){ d = 9; blk = bb;       }
    else if (bb < 320){ d = 8; blk = bb - 256; }
    else if (bb < 336){ d = 7; blk = bb - 320; }
    else if (bb < 340){ d = 6; blk = bb - 336; }
    else              { d = 5; blk = bb - 340; }
    size_t base = (size_t)OFFS[d] + (size_t)blk*1024;
    emb_pair(h, EH, ELo, embB, lng, lnb, gain, d,
             base + (size_t)w*16, base + (size_t)(w+16)*16, lane);
    emb_pair(h, EH, ELo, embB, lng, lnb, gain, d,
             base + (size_t)(w+32)*16, base + (size_t)(w+48)*16, lane);
    return;
  }
  // ---- block 0: tail levels 3..1 + emb levels 0..4 ----
  for (int e = t; e < 21*16; e += 1024)
    ((float4*)Hpar)[e] = ((const float4*)h)[e];
  for (int e = t; e < 65*16; e += 1024){
    int node = e >> 4, u = e & 15;
    float4 r = make_float4(0.f,0.f,0.f,0.f);
    if (node < 64){
      const float4* c = (const float4*)(h + (size_t)(OFFS[4] + 4*node)*64) + u;
      float4 c0 = c[0], c1 = c[16], c2 = c[32], c3 = c[48];
      float4 pr = *((const float4*)(h + (size_t)(OFFS[3] + node)*64) + u);
      r.x = 0.25f*(c0.x+c1.x+c2.x+c3.x) + pr.x;
      r.y = 0.25f*(c0.y+c1.y+c2.y+c3.y) + pr.y;
      r.z = 0.25f*(c0.z+c1.z+c2.z+c3.z) + pr.z;
      r.w = 0.25f*(c0.w+c1.w+c2.w+c3.w) + pr.w;
    }
    unsigned short h0=f2bh(r.x), h1=f2bh(r.y), h2=f2bh(r.z), h3=f2bh(r.w);
    *(ushort4*)&PtH[node*72 + u*4] = make_ushort4(h0,h1,h2,h3);
    *(ushort4*)&PtL[node*72 + u*4] = make_ushort4(
        f2bh(r.x - bh2f(h0)), f2bh(r.y - bh2f(h1)),
        f2bh(r.z - bh2f(h2)), f2bh(r.w - bh2f(h3)));
  }
  __syncthreads();
  tail_level2<3>(h, WH + (size_t)2*36864, WLo + (size_t)2*36864, convB, Hpar, PtH, PtL, t);
  tail_level2<2>(h, WH + (size_t)1*36864, WLo + (size_t)1*36864, convB, Hpar, PtH, PtL, t);
  tail_level2<1>(h, WH,                   WLo,                   convB, Hpar, PtH, PtL, t);
  // epilogue: emb levels 0..4 (23 tile-jobs over 16 waves)
  for (int j = w; j < 23; j += 16){
    int d, tile;
    if (j < 16)      { d=4; tile=j;    }
    else if (j < 20) { d=3; tile=j-16; }
    else if (j == 20){ d=2; tile=0;    }
    else if (j == 21){ d=1; tile=0;    }
    else             { d=0; tile=0;    }
    int Nlev = 1 << (2*d);
    int valid = Nlev - tile*16;
    emb_tile(h, EH, ELo, embB, lng, lnb, gain, d,
             (size_t)OFFS[d] + (size_t)tile*16, valid > 16 ? 16 : valid, lane);
  }
}

extern "C" void kernel_launch(void* const* d_in, const int* in_sizes, int n_in,
                              void* d_out, int out_size, void* d_ws, size_t ws_size,
                              hipStream_t stream) {
  (void)in_sizes; (void)n_in; (void)out_size;
  const float* feat  = (const float*)d_in[0];
  const float* ipW   = (const float*)d_in[1];
  const float* ipB   = (const float*)d_in[2];
  const float* convW = (const float*)d_in[3];
  const float* convB = (const float*)d_in[4];
  const float* embW  = (const float*)d_in[5];
  const float* embB  = (const float*)d_in[6];
  const float* lng   = (const float*)d_in[7];
  const float* lnb   = (const float*)d_in[8];
  const float* gain  = (const float*)d_in[9];
  float* h = (float*)d_out;

  unsigned short* WH  = (unsigned short*)d_ws;
  unsigned short* WLo = WH + FRAG_USH;
  const unsigned short* EH  = WH  + CONV_USH;
  const unsigned short* ELo = WLo + CONV_USH;
  float* hpre = (ws_size >= FRAG_BYTES + HPRE_BYTES)
              ? (float*)((char*)d_ws + FRAG_BYTES) : nullptr;

  // 1: merged W-prep + inproj
  k_prep<<<WPREP_BLOCKS + INPROJ_BLOCKS, 256, 0, stream>>>(
      convW, embW, WH, WLo, feat, ipW, ipB, h, hpre);

  // 2..6: bare conv L=8..4
  for (int L = 8; L >= 4; --L){
    int Np = 1 << (2*L);
    const float* hPar = hpre ? (hpre + (size_t)(OFFS[L] - OFFS[4])*64)
                             : (h + (size_t)OFFS[L]*64);
    k_conv<<<Np/64, 256, 0, stream>>>(h, hPar,
        WH  + (size_t)(L-1)*36864, WLo + (size_t)(L-1)*36864,
        convB + (size_t)L*64, Np, OFFS[L], OFFS[L+1], L);
  }

  // 7: final — 16-wave tail + all emb (levels 5..9, 1024-node blocks, regular stores)
  k_final<<<1 + 341, 1024, 0, stream>>>(h, WH, WLo, convB,
      EH, ELo, embB, lng, lnb, gain);
}

// Round 24
// 180.804 us; speedup vs baseline: 1.1427x; 1.1289x over previous
//
#include <hip/hip_runtime.h>
#include <hip/hip_bf16.h>

static constexpr int TOTAL = 349525;
static constexpr int OFFS[11] = {0,1,5,21,85,341,1365,5461,21845,87381,349525};
static constexpr size_t CONV_USH = (size_t)8*9*2*4*64*8;    // 294912 ushorts
static constexpr size_t EMB_USH  = (size_t)10*2*4*64*8;     //  40960 ushorts
static constexpr size_t FRAG_USH = CONV_USH + EMB_USH;      // 335872
static constexpr size_t FRAG_BYTES = FRAG_USH*2*2;          // 1343488 B
static constexpr size_t HPRE_BYTES = (size_t)(87381-85)*64*4;
static constexpr int WPREP_BLOCKS = 164;
static constexpr int INPROJ_BLOCKS = (TOTAL + 127)/128;     // 2731

typedef __attribute__((ext_vector_type(8))) short short8;
typedef __attribute__((ext_vector_type(4))) float f32x4;

__device__ __forceinline__ unsigned deint(unsigned v){
  v &= 0x55555555u;
  v = (v | (v>>1)) & 0x33333333u;
  v = (v | (v>>2)) & 0x0F0F0F0Fu;
  v = (v | (v>>4)) & 0x00FF00FFu;
  v = (v | (v>>8)) & 0x0000FFFFu;
  return v;
}
__device__ __forceinline__ unsigned ileave(unsigned v){
  v &= 0xFFFFu;
  v = (v | (v<<8)) & 0x00FF00FFu;
  v = (v | (v<<4)) & 0x0F0F0F0Fu;
  v = (v | (v<<2)) & 0x33333333u;
  v = (v | (v<<1)) & 0x55555555u;
  return v;
}
__device__ __forceinline__ unsigned short f2bh(float x){
  unsigned u = __float_as_uint(x);
  return (unsigned short)((u + 0x7FFFu + ((u>>16)&1u)) >> 16);
}
__device__ __forceinline__ float bh2f(unsigned short h){
  return __uint_as_float(((unsigned)h) << 16);
}
__device__ __forceinline__ void split8(float4 a, float4 b, short8 &hi, short8 &lo){
  float v[8] = {a.x,a.y,a.z,a.w,b.x,b.y,b.z,b.w};
  unsigned short hv[8], lv[8];
  #pragma unroll
  for (int j=0;j<8;++j){ hv[j]=f2bh(v[j]); lv[j]=f2bh(v[j]-bh2f(hv[j])); }
  hi = short8{(short)hv[0],(short)hv[1],(short)hv[2],(short)hv[3],
              (short)hv[4],(short)hv[5],(short)hv[6],(short)hv[7]};
  lo = short8{(short)lv[0],(short)lv[1],(short)lv[2],(short)lv[3],
              (short)lv[4],(short)lv[5],(short)lv[6],(short)lv[7]};
}

// ---------- merged prep: blocks <164 = W-frag prep; rest = inproj (verified) ----------
__global__ __launch_bounds__(256) void k_prep(const float* __restrict__ convW,
    const float* __restrict__ embW,
    unsigned short* __restrict__ WH, unsigned short* __restrict__ WLo,
    const float* __restrict__ feat, const float* __restrict__ ipW,
    const float* __restrict__ ipB, float* __restrict__ h,
    float* __restrict__ hpre){
  __shared__ float Alt[128][44];
  __shared__ float Wl[40][68];
  int t = threadIdx.x;
  if ((int)blockIdx.x < WPREP_BLOCKS){
    int tid = blockIdx.x*256 + t;
    if (tid >= 41984) return;
    const float* src;
    size_t dst;
    if (tid < 36864){
      int l=tid&63, cb=(tid>>6)&3, ks=(tid>>8)&1;
      int x=tid>>9; int m=x%9, Lp=x/9;
      int k0=ks*32+((l>>4)<<3), ch=cb*16+(l&15);
      src = convW + (size_t)(Lp+1)*36864 + (size_t)(m*64+k0)*64 + ch;
      dst = (size_t)tid*8;
    } else {
      int t2 = tid - 36864;
      int l=t2&63, cb=(t2>>6)&3, ks=(t2>>8)&1, d=t2>>9;
      int k0=ks*32+((l>>4)<<3), ch=cb*16+(l&15);
      src = embW + (size_t)d*4096 + (size_t)k0*64 + ch;
      dst = CONV_USH + (size_t)t2*8;
    }
    unsigned short hv[8], lv[8];
    #pragma unroll
    for (int j=0;j<8;++j){
      float v = src[(size_t)j*64];
      unsigned short hh = f2bh(v);
      hv[j] = hh;
      lv[j] = f2bh(v - bh2f(hh));
    }
    short8 vh = {(short)hv[0],(short)hv[1],(short)hv[2],(short)hv[3],
                 (short)hv[4],(short)hv[5],(short)hv[6],(short)hv[7]};
    short8 vl = {(short)lv[0],(short)lv[1],(short)lv[2],(short)lv[3],
                 (short)lv[4],(short)lv[5],(short)lv[6],(short)lv[7]};
    *(short8*)(WH  + dst) = vh;
    *(short8*)(WLo + dst) = vl;
    return;
  }
  int base = ((int)blockIdx.x - WPREP_BLOCKS) * 128;
  for (int idx = t; idx < 40*64; idx += 256)
    Wl[idx >> 6][idx & 63] = ipW[idx];
  if (t < 128){
    int g = base + t;
    float* row = Alt[t];
    if (g < TOTAL){
      int d = 0;
      #pragma unroll
      for (int i = 1; i <= 9; ++i) if (g >= OFFS[i]) d = i;
      int local = g - OFFS[d];
      unsigned ix = deint((unsigned)local), iy = deint(((unsigned)local) >> 1);
      float inv = 1.0f / (float)(1 << d);
      float px = ((float)ix + 0.5f) * inv;
      float py = ((float)iy + 0.5f) * inv;
      float pd = (float)d * (1.0f/9.0f);
      row[0] = feat[g]; row[1] = px; row[2] = py; row[3] = pd;
      float p3[3] = {px, py, pd};
      #pragma unroll
      for (int c = 0; c < 3; ++c){
        float s, co;
        __sincosf(6.28318530717958647692f * p3[c], &s, &co);
        float* rb = row + 4 + c*12;
        #pragma unroll
        for (int f = 0; f < 6; ++f){
          rb[f] = s; rb[6+f] = co;
          float s2 = 2.f*s*co, c2 = 1.f - 2.f*s*s;
          s = s2; co = c2;
        }
      }
    } else {
      #pragma unroll
      for (int k = 0; k < 40; ++k) row[k] = 0.f;
    }
  }
  __syncthreads();
  int tr = t >> 3, tc = t & 7;
  float acc[4][8];
  #pragma unroll
  for (int i=0;i<4;++i)
    #pragma unroll
    for (int c=0;c<8;++c) acc[i][c] = 0.f;
  #pragma unroll 2
  for (int k4 = 0; k4 < 10; ++k4){
    float av4[4][4];
    #pragma unroll
    for (int i=0;i<4;++i){
      float4 aa = *(const float4*)&Alt[tr*4+i][k4*4];
      av4[i][0]=aa.x; av4[i][1]=aa.y; av4[i][2]=aa.z; av4[i][3]=aa.w;
    }
    #pragma unroll
    for (int j=0;j<4;++j){
      float4 lo = *(const float4*)&Wl[k4*4+j][tc*8];
      float4 hi = *(const float4*)&Wl[k4*4+j][tc*8+4];
      float wv[8];
      wv[0]=lo.x; wv[1]=lo.y; wv[2]=lo.z; wv[3]=lo.w;
      wv[4]=hi.x; wv[5]=hi.y; wv[6]=hi.z; wv[7]=hi.w;
      #pragma unroll
      for (int i=0;i<4;++i){
        float a = av4[i][j];
        #pragma unroll
        for (int c=0;c<8;++c) acc[i][c] += a*wv[c];
      }
    }
  }
  #pragma unroll
  for (int i=0;i<4;++i){
    int g = base + tr*4 + i;
    if (g >= TOTAL) continue;
    float ov[8];
    #pragma unroll
    for (int c=0;c<8;++c) ov[c] = acc[i][c] + ipB[tc*8+c];
    float* dst = &h[(size_t)g*64 + tc*8];
    *(float4*)dst       = *(const float4*)&ov[0];
    *(float4*)(dst + 4) = *(const float4*)&ov[4];
    if (hpre && g >= OFFS[4] && g < OFFS[9]){
      float* dp = hpre + (size_t)(g - OFFS[4])*64 + tc*8;
      *(float4*)dp       = *(const float4*)&ov[0];
      *(float4*)(dp + 4) = *(const float4*)&ov[4];
    }
  }
}

// ---------- conv body (verified): halo + fused pool + MFMA bf16-split ----------
__device__ __forceinline__ void conv_dev(float* __restrict__ h,
    const float* __restrict__ hPar,
    const unsigned short* __restrict__ WHl, const unsigned short* __restrict__ WLl,
    const float* __restrict__ Bb, int N, int offL, int offC, int lbits, int bnum,
    unsigned short* haloH, unsigned short* haloL, int* hkey, int t){
  int nb = bnum * 64;
  int res = 1 << lbits;
  if (t < 100){
    int i = t % 10, j = t / 10;
    int gx = (int)deint((unsigned)nb) - 1 + i;
    int gy = (int)deint(((unsigned)nb)>>1) - 1 + j;
    bool ok = (gx>=0 && gy>=0 && gx<res && gy<res);
    hkey[t] = ok ? (int)(ileave((unsigned)gx) | (ileave((unsigned)gy)<<1)) : -1;
  }
  __syncthreads();
  const float* hC = h + (size_t)offC*64;
  for (int e = t; e < 1600; e += 256){
    int hi_ = e >> 4, u = e & 15;
    int key = hkey[hi_];
    float4 r = make_float4(0.f,0.f,0.f,0.f);
    if (key >= 0){
      const float4* c = (const float4*)(hC + (size_t)(4*key)*64) + u;
      float4 c0 = c[0], c1 = c[16], c2 = c[32], c3 = c[48];
      float4 pr = *((const float4*)(hPar + (size_t)key*64) + u);
      r.x = 0.25f*(c0.x+c1.x+c2.x+c3.x) + pr.x;
      r.y = 0.25f*(c0.y+c1.y+c2.y+c3.y) + pr.y;
      r.z = 0.25f*(c0.z+c1.z+c2.z+c3.z) + pr.z;
      r.w = 0.25f*(c0.w+c1.w+c2.w+c3.w) + pr.w;
    }
    unsigned short h0=f2bh(r.x), h1=f2bh(r.y), h2=f2bh(r.z), h3=f2bh(r.w);
    *(ushort4*)&haloH[hi_*72 + u*4] = make_ushort4(h0,h1,h2,h3);
    *(ushort4*)&haloL[hi_*72 + u*4] = make_ushort4(
        f2bh(r.x - bh2f(h0)), f2bh(r.y - bh2f(h1)),
        f2bh(r.z - bh2f(h2)), f2bh(r.w - bh2f(h3)));
  }
  __syncthreads();
  int cb   = __builtin_amdgcn_readfirstlane(t >> 6);
  int lane = t & 63;
  int q = lane >> 4;
  int chl = cb*16 + (lane & 15);
  int lx0,ly0,lx1,ly1,lx2,ly2,lx3,ly3;
  {
    int n0 = (lane&15), n1 = 16+(lane&15), n2 = 32+(lane&15), n3 = 48+(lane&15);
    lx0=(int)deint((unsigned)n0); ly0=(int)deint(((unsigned)n0)>>1);
    lx1=(int)deint((unsigned)n1); ly1=(int)deint(((unsigned)n1)>>1);
    lx2=(int)deint((unsigned)n2); ly2=(int)deint(((unsigned)n2)>>1);
    lx3=(int)deint((unsigned)n3); ly3=(int)deint(((unsigned)n3)>>1);
  }
  f32x4 acc0 = {0.f,0.f,0.f,0.f}, acc1 = acc0, acc2 = acc0, acc3 = acc0;
  #pragma unroll 1
  for (int dy=0;dy<3;++dy){
    #pragma unroll 1
    for (int dx=0;dx<3;++dx){
      int m = dy*3 + dx;
      int r0 = (ly0+dy)*10 + lx0+dx;
      int r1 = (ly1+dy)*10 + lx1+dx;
      int r2 = (ly2+dy)*10 + lx2+dx;
      int r3 = (ly3+dy)*10 + lx3+dx;
      #pragma unroll
      for (int ks=0;ks<2;++ks){
        const unsigned short* fp = WHl + ((size_t)((m*2+ks)*4 + cb)*64 + lane)*8;
        const unsigned short* fq = WLl + ((size_t)((m*2+ks)*4 + cb)*64 + lane)*8;
        short8 bh = *(const short8*)fp;
        short8 bl = *(const short8*)fq;
        int so = (ks*4 + q)*8;
        short8 ah0 = *(const short8*)&haloH[r0*72 + so];
        short8 al0 = *(const short8*)&haloL[r0*72 + so];
        short8 ah1 = *(const short8*)&haloH[r1*72 + so];
        short8 al1 = *(const short8*)&haloL[r1*72 + so];
        short8 ah2 = *(const short8*)&haloH[r2*72 + so];
        short8 al2 = *(const short8*)&haloL[r2*72 + so];
        short8 ah3 = *(const short8*)&haloH[r3*72 + so];
        short8 al3 = *(const short8*)&haloL[r3*72 + so];
        acc0 = __builtin_amdgcn_mfma_f32_16x16x32_bf16(ah0, bh, acc0, 0,0,0);
        acc1 = __builtin_amdgcn_mfma_f32_16x16x32_bf16(ah1, bh, acc1, 0,0,0);
        acc2 = __builtin_amdgcn_mfma_f32_16x16x32_bf16(ah2, bh, acc2, 0,0,0);
        acc3 = __builtin_amdgcn_mfma_f32_16x16x32_bf16(ah3, bh, acc3, 0,0,0);
        acc0 = __builtin_amdgcn_mfma_f32_16x16x32_bf16(al0, bh, acc0, 0,0,0);
        acc1 = __builtin_amdgcn_mfma_f32_16x16x32_bf16(al1, bh, acc1, 0,0,0);
        acc2 = __builtin_amdgcn_mfma_f32_16x16x32_bf16(al2, bh, acc2, 0,0,0);
        acc3 = __builtin_amdgcn_mfma_f32_16x16x32_bf16(al3, bh, acc3, 0,0,0);
        acc0 = __builtin_amdgcn_mfma_f32_16x16x32_bf16(ah0, bl, acc0, 0,0,0);
        acc1 = __builtin_amdgcn_mfma_f32_16x16x32_bf16(ah1, bl, acc1, 0,0,0);
        acc2 = __builtin_amdgcn_mfma_f32_16x16x32_bf16(ah2, bl, acc2, 0,0,0);
        acc3 = __builtin_amdgcn_mfma_f32_16x16x32_bf16(ah3, bl, acc3, 0,0,0);
      }
    }
  }
  float bias = Bb[chl];
  int rowb = q*4;
  float* hO = h + (size_t)(offL + nb)*64;
  #pragma unroll
  for (int reg=0;reg<4;++reg){
    int n0 = rowb + reg;
    float v0 = acc0[reg] + bias; if (nb + n0      < N) hO[(size_t)(n0     )*64 + chl] = v0 > 0.f ? v0 : 0.f;
    float v1 = acc1[reg] + bias; if (nb + n0 + 16 < N) hO[(size_t)(n0 + 16)*64 + chl] = v1 > 0.f ? v1 : 0.f;
    float v2 = acc2[reg] + bias; if (nb + n0 + 32 < N) hO[(size_t)(n0 + 32)*64 + chl] = v2 > 0.f ? v2 : 0.f;
    float v3 = acc3[reg] + bias; if (nb + n0 + 48 < N) hO[(size_t)(n0 + 48)*64 + chl] = v3 > 0.f ? v3 : 0.f;
  }
}

// ---------- conv launch (bare) ----------
__global__ __launch_bounds__(256) void k_conv(float* __restrict__ h,
    const float* __restrict__ hPar,
    const unsigned short* __restrict__ WHl, const unsigned short* __restrict__ WLl,
    const float* __restrict__ Bb, int N, int offL, int offC, int lbits){
  __shared__ unsigned short haloH[100*72];
  __shared__ unsigned short haloL[100*72];
  __shared__ int hkey[100];
  conv_dev(h, hPar, WHl, WLl, Bb, N, offL, offC, lbits, blockIdx.x,
           haloH, haloL, hkey, threadIdx.x);
}

// ---------- emb tile (verified; used by tail epilogue) ----------
__device__ __forceinline__ void emb_tile(float* __restrict__ h,
    const unsigned short* __restrict__ EH, const unsigned short* __restrict__ ELo,
    const float* __restrict__ embB, const float* __restrict__ lng,
    const float* __restrict__ lnb, const float* __restrict__ gain,
    int d, size_t rowbase, int validN, int lane){
  int q = lane >> 4, li = lane & 15;
  const float* rp = h + (rowbase + li)*64 + q*8;
  float4 a0 = *(const float4*)rp;
  float4 a1 = *(const float4*)(rp + 4);
  float4 a2 = *(const float4*)(rp + 32);
  float4 a3 = *(const float4*)(rp + 36);
  short8 ah0, al0, ah1, al1;
  split8(a0, a1, ah0, al0);
  split8(a2, a3, ah1, al1);
  f32x4 acc0 = {0.f,0.f,0.f,0.f}, acc1 = acc0, acc2 = acc0, acc3 = acc0;
  #define EMB_CB(CB, ACC) { \
    size_t f0 = (((size_t)(d*2+0)*4 + (CB))*64 + lane)*8; \
    size_t f1 = (((size_t)(d*2+1)*4 + (CB))*64 + lane)*8; \
    short8 bh0 = *(const short8*)(EH + f0); \
    short8 bl0 = *(const short8*)(ELo + f0); \
    short8 bh1 = *(const short8*)(EH + f1); \
    short8 bl1 = *(const short8*)(ELo + f1); \
    ACC = __builtin_amdgcn_mfma_f32_16x16x32_bf16(ah0, bh0, ACC, 0,0,0); \
    ACC = __builtin_amdgcn_mfma_f32_16x16x32_bf16(al0, bh0, ACC, 0,0,0); \
    ACC = __builtin_amdgcn_mfma_f32_16x16x32_bf16(ah0, bl0, ACC, 0,0,0); \
    ACC = __builtin_amdgcn_mfma_f32_16x16x32_bf16(ah1, bh1, ACC, 0,0,0); \
    ACC = __builtin_amdgcn_mfma_f32_16x16x32_bf16(al1, bh1, ACC, 0,0,0); \
    ACC = __builtin_amdgcn_mfma_f32_16x16x32_bf16(ah1, bl1, ACC, 0,0,0); }
  EMB_CB(0, acc0)
  EMB_CB(1, acc1)
  EMB_CB(2, acc2)
  EMB_CB(3, acc3)
  #undef EMB_CB
  float b0 = embB[d*64 +      li];
  float b1 = embB[d*64 + 16 + li];
  float b2 = embB[d*64 + 32 + li];
  float b3 = embB[d*64 + 48 + li];
  float mu[4], rs[4];
  float z0[4], z1[4], z2[4], z3[4];
  #pragma unroll
  for (int r=0;r<4;++r){
    z0[r] = acc0[r] + b0;
    z1[r] = acc1[r] + b1;
    z2[r] = acc2[r] + b2;
    z3[r] = acc3[r] + b3;
    float s  = z0[r] + z1[r] + z2[r] + z3[r];
    float qv = z0[r]*z0[r] + z1[r]*z1[r] + z2[r]*z2[r] + z3[r]*z3[r];
    #pragma unroll
    for (int mk=1; mk<16; mk<<=1){
      s  += __shfl_xor(s, mk, 64);
      qv += __shfl_xor(qv, mk, 64);
    }
    float m = s * 0.015625f;
    mu[r] = m;
    rs[r] = rsqrtf(qv * 0.015625f - m*m + 1e-5f);
  }
  float g0 = lng[d*64 +      li], l0 = lnb[d*64 +      li];
  float g1 = lng[d*64 + 16 + li], l1 = lnb[d*64 + 16 + li];
  float g2 = lng[d*64 + 32 + li], l2 = lnb[d*64 + 32 + li];
  float g3 = lng[d*64 + 48 + li], l3 = lnb[d*64 + 48 + li];
  float gn = gain[d];
  #pragma unroll
  for (int r=0;r<4;++r){
    int ni = q*4 + r;
    if (ni < validN){
      float* row = h + (rowbase + ni)*64;
      row[     li] = ((z0[r] - mu[r])*rs[r]*g0 + l0)*gn;
      row[16 + li] = ((z1[r] - mu[r])*rs[r]*g1 + l1)*gn;
      row[32 + li] = ((z2[r] - mu[r])*rs[r]*g2 + l2)*gn;
      row[48 + li] = ((z3[r] - mu[r])*rs[r]*g3 + l3)*gn;
    }
  }
}

// ---------- pipelined emb pair (verified): both tiles' A-loads up front ----------
__device__ __forceinline__ void emb_pair(float* __restrict__ h,
    const unsigned short* __restrict__ EH, const unsigned short* __restrict__ ELo,
    const float* __restrict__ embB, const float* __restrict__ lng,
    const float* __restrict__ lnb, const float* __restrict__ gain,
    int d, size_t rb1, size_t rb2, int lane){
  int q = lane >> 4, li = lane & 15;
  const float* rp1 = h + (rb1 + li)*64 + q*8;
  const float* rp2 = h + (rb2 + li)*64 + q*8;
  float4 x0 = *(const float4*)rp1;
  float4 x1 = *(const float4*)(rp1 + 4);
  float4 x2 = *(const float4*)(rp1 + 32);
  float4 x3 = *(const float4*)(rp1 + 36);
  float4 y0 = *(const float4*)rp2;
  float4 y1 = *(const float4*)(rp2 + 4);
  float4 y2 = *(const float4*)(rp2 + 32);
  float4 y3 = *(const float4*)(rp2 + 36);
  short8 Xh0, Xl0, Xh1, Xl1, Yh0, Yl0, Yh1, Yl1;
  split8(x0, x1, Xh0, Xl0);
  split8(x2, x3, Xh1, Xl1);
  split8(y0, y1, Yh0, Yl0);
  split8(y2, y3, Yh1, Yl1);
  f32x4 pA0 = {0.f,0.f,0.f,0.f}, pA1 = pA0, pA2 = pA0, pA3 = pA0;
  f32x4 pB0 = pA0, pB1 = pA0, pB2 = pA0, pB3 = pA0;
  #define EMB_CB2(CB, ACCA, ACCB) { \
    size_t f0 = (((size_t)(d*2+0)*4 + (CB))*64 + lane)*8; \
    size_t f1 = (((size_t)(d*2+1)*4 + (CB))*64 + lane)*8; \
    short8 bh0 = *(const short8*)(EH + f0); \
    short8 bl0 = *(const short8*)(ELo + f0); \
    short8 bh1 = *(const short8*)(EH + f1); \
    short8 bl1 = *(const short8*)(ELo + f1); \
    ACCA = __builtin_amdgcn_mfma_f32_16x16x32_bf16(Xh0, bh0, ACCA, 0,0,0); \
    ACCB = __builtin_amdgcn_mfma_f32_16x16x32_bf16(Yh0, bh0, ACCB, 0,0,0); \
    ACCA = __builtin_amdgcn_mfma_f32_16x16x32_bf16(Xl0, bh0, ACCA, 0,0,0); \
    ACCB = __builtin_amdgcn_mfma_f32_16x16x32_bf16(Yl0, bh0, ACCB, 0,0,0); \
    ACCA = __builtin_amdgcn_mfma_f32_16x16x32_bf16(Xh0, bl0, ACCA, 0,0,0); \
    ACCB = __builtin_amdgcn_mfma_f32_16x16x32_bf16(Yh0, bl0, ACCB, 0,0,0); \
    ACCA = __builtin_amdgcn_mfma_f32_16x16x32_bf16(Xh1, bh1, ACCA, 0,0,0); \
    ACCB = __builtin_amdgcn_mfma_f32_16x16x32_bf16(Yh1, bh1, ACCB, 0,0,0); \
    ACCA = __builtin_amdgcn_mfma_f32_16x16x32_bf16(Xl1, bh1, ACCA, 0,0,0); \
    ACCB = __builtin_amdgcn_mfma_f32_16x16x32_bf16(Yl1, bh1, ACCB, 0,0,0); \
    ACCA = __builtin_amdgcn_mfma_f32_16x16x32_bf16(Xh1, bl1, ACCA, 0,0,0); \
    ACCB = __builtin_amdgcn_mfma_f32_16x16x32_bf16(Yh1, bl1, ACCB, 0,0,0); }
  EMB_CB2(0, pA0, pB0)
  EMB_CB2(1, pA1, pB1)
  EMB_CB2(2, pA2, pB2)
  EMB_CB2(3, pA3, pB3)
  #undef EMB_CB2
  float b0 = embB[d*64 +      li];
  float b1 = embB[d*64 + 16 + li];
  float b2 = embB[d*64 + 32 + li];
  float b3 = embB[d*64 + 48 + li];
  float g0 = lng[d*64 +      li], l0 = lnb[d*64 +      li];
  float g1 = lng[d*64 + 16 + li], l1 = lnb[d*64 + 16 + li];
  float g2 = lng[d*64 + 32 + li], l2 = lnb[d*64 + 32 + li];
  float g3 = lng[d*64 + 48 + li], l3 = lnb[d*64 + 48 + li];
  float gn = gain[d];
  #define EMB_FIN(ACC0, ACC1, ACC2, ACC3, RB) { \
    _Pragma("unroll") \
    for (int r=0;r<4;++r){ \
      float z0 = ACC0[r] + b0, z1 = ACC1[r] + b1; \
      float z2 = ACC2[r] + b2, z3 = ACC3[r] + b3; \
      float s  = z0 + z1 + z2 + z3; \
      float qv = z0*z0 + z1*z1 + z2*z2 + z3*z3; \
      _Pragma("unroll") \
      for (int mk=1; mk<16; mk<<=1){ \
        s  += __shfl_xor(s, mk, 64); \
        qv += __shfl_xor(qv, mk, 64); \
      } \
      float m = s * 0.015625f; \
      float rsv = rsqrtf(qv * 0.015625f - m*m + 1e-5f); \
      float* row = h + ((RB) + (size_t)(q*4 + r))*64; \
      row[     li] = ((z0 - m)*rsv*g0 + l0)*gn; \
      row[16 + li] = ((z1 - m)*rsv*g1 + l1)*gn; \
      row[32 + li] = ((z2 - m)*rsv*g2 + l2)*gn; \
      row[48 + li] = ((z3 - m)*rsv*g3 + l3)*gn; \
    } }
  EMB_FIN(pA0, pA1, pA2, pA3, rb1)
  EMB_FIN(pB0, pB1, pB2, pB3, rb2)
  #undef EMB_FIN
}

// ---------- tail level, 1024-thread 16-wave variant (verified) ----------
template<int L>
__device__ __forceinline__ void tail_level2(float* __restrict__ h,
    const unsigned short* __restrict__ WHc, const unsigned short* __restrict__ WLc,
    const float* __restrict__ convB, const float* __restrict__ Hpar,
    unsigned short* __restrict__ PtH, unsigned short* __restrict__ PtL, int t){
  constexpr int Np  = 1 << (2*L);
  constexpr int NTt = (Np + 15)/16;
  constexpr int TG  = (NTt + 3)/4;
  constexpr int res = 1 << L;
  int w  = t >> 6;
  int cb = __builtin_amdgcn_readfirstlane(w & 3);
  int tg = __builtin_amdgcn_readfirstlane(w >> 2);
  int lane = t & 63;
  int q = lane >> 4, li = lane & 15;
  int chl = cb*16 + li;
  int lx[TG], ly[TG];
  #pragma unroll
  for (int i=0;i<TG;++i){
    unsigned n = (unsigned)((tg*TG + i)*16 + li);
    lx[i] = (int)deint(n); ly[i] = (int)deint(n >> 1);
  }
  f32x4 acc[TG];
  #pragma unroll
  for (int i=0;i<TG;++i) acc[i] = f32x4{0.f,0.f,0.f,0.f};
  short8 bh0, bl0, bh1, bl1;
  {
    size_t f0 = ((size_t)(0*4 + cb)*64 + lane)*8;
    size_t f1 = ((size_t)(1*4 + cb)*64 + lane)*8;
    bh0 = *(const short8*)(WHc + f0); bl0 = *(const short8*)(WLc + f0);
    bh1 = *(const short8*)(WHc + f1); bl1 = *(const short8*)(WLc + f1);
  }
  #pragma unroll 1
  for (int m=0;m<9;++m){
    short8 nh0, nl0, nh1, nl1;
    if (m < 8){
      size_t f0 = ((size_t)(((m+1)*2+0)*4 + cb)*64 + lane)*8;
      size_t f1 = ((size_t)(((m+1)*2+1)*4 + cb)*64 + lane)*8;
      nh0 = *(const short8*)(WHc + f0); nl0 = *(const short8*)(WLc + f0);
      nh1 = *(const short8*)(WHc + f1); nl1 = *(const short8*)(WLc + f1);
    }
    int dy = m/3 - 1, dx = m%3 - 1;
    #pragma unroll
    for (int i=0;i<TG;++i){
      int nx = lx[i]+dx, ny = ly[i]+dy;
      int key = (nx>=0 && ny>=0 && nx<res && ny<res)
              ? (int)(ileave((unsigned)nx) | (ileave((unsigned)ny)<<1)) : Np;
      const unsigned short* pH = PtH + key*72;
      const unsigned short* pL = PtL + key*72;
      short8 ah0 = *(const short8*)(pH + q*8);
      short8 al0 = *(const short8*)(pL + q*8);
      short8 ah1 = *(const short8*)(pH + 32 + q*8);
      short8 al1 = *(const short8*)(pL + 32 + q*8);
      acc[i] = __builtin_amdgcn_mfma_f32_16x16x32_bf16(ah0, bh0, acc[i], 0,0,0);
      acc[i] = __builtin_amdgcn_mfma_f32_16x16x32_bf16(al0, bh0, acc[i], 0,0,0);
      acc[i] = __builtin_amdgcn_mfma_f32_16x16x32_bf16(ah0, bl0, acc[i], 0,0,0);
      acc[i] = __builtin_amdgcn_mfma_f32_16x16x32_bf16(ah1, bh1, acc[i], 0,0,0);
      acc[i] = __builtin_amdgcn_mfma_f32_16x16x32_bf16(al1, bh1, acc[i], 0,0,0);
      acc[i] = __builtin_amdgcn_mfma_f32_16x16x32_bf16(ah1, bl1, acc[i], 0,0,0);
    }
    if (m < 8){ bh0 = nh0; bl0 = nl0; bh1 = nh1; bl1 = nl1; }
  }
  float bias = convB[L*64 + chl];
  float vq[TG][4];
  #pragma unroll
  for (int i=0;i<TG;++i){
    #pragma unroll
    for (int reg=0;reg<4;++reg){
      int ni = (tg*TG + i)*16 + q*4 + reg;
      float v = acc[i][reg] + bias;
      v = v > 0.f ? v : 0.f;
      vq[i][reg] = v;
      if (ni < Np) h[(size_t)(OFFS[L] + ni)*64 + chl] = v;
    }
  }
  __syncthreads();
  if (L > 1){
    constexpr int Pp = Np/4;
    #pragma unroll
    for (int i=0;i<TG;++i){
      int p = (tg*TG + i)*4 + q;
      if (p < Pp){
        float pooled = 0.25f*(vq[i][0]+vq[i][1]+vq[i][2]+vq[i][3])
                     + Hpar[(size_t)(OFFS[L-1] + p)*64 + chl];
        unsigned short hh = f2bh(pooled);
        PtH[p*72 + chl] = hh;
        PtL[p*72 + chl] = f2bh(pooled - bh2f(hh));
      }
    }
    if (t < 64){ PtH[Pp*72 + t] = 0; PtL[Pp*72 + t] = 0; }
  } else {
    if (tg == 0 && q == 0){
      float pooled = 0.25f*(vq[0][0]+vq[0][1]+vq[0][2]+vq[0][3]) + Hpar[chl];
      h[chl] = pooled;
    }
  }
  __syncthreads();
}

// ---------- final launch (1024 thr): block 0 = 16-wave tail + emb0..4; 1.. = emb512 ----------
__global__ __launch_bounds__(1024) void k_final(float* __restrict__ h,
    const unsigned short* __restrict__ WH, const unsigned short* __restrict__ WLo,
    const float* __restrict__ convB,
    const unsigned short* __restrict__ EH, const unsigned short* __restrict__ ELo,
    const float* __restrict__ embB, const float* __restrict__ lng,
    const float* __restrict__ lnb, const float* __restrict__ gain){
  __shared__ __align__(16) char smem[24128];
  unsigned short* PtH = (unsigned short*)smem;               //  9360 B
  unsigned short* PtL = (unsigned short*)(smem + 9360);      //  9360 B
  float* Hpar = (float*)(smem + 18720);                      //  5376 B
  int t = threadIdx.x;
  int w = t >> 6, lane = t & 63;
  int b = blockIdx.x;
  if (b != 0){
    int bb = b - 1;
    int d, blk;
    if      (bb < 512){ d = 9; blk = bb;       }
    else if (bb < 640){ d = 8; blk = bb - 512; }
    else if (bb < 672){ d = 7; blk = bb - 640; }
    else if (bb < 680){ d = 6; blk = bb - 672; }
    else              { d = 5; blk = bb - 680; }
    size_t base = (size_t)OFFS[d] + (size_t)blk*512;
    emb_pair(h, EH, ELo, embB, lng, lnb, gain, d,
             base + (size_t)w*16, base + (size_t)(w+16)*16, lane);
    return;
  }
  // ---- block 0: tail levels 3..1 + emb levels 0..4 ----
  for (int e = t; e < 21*16; e += 1024)
    ((float4*)Hpar)[e] = ((const float4*)h)[e];
  for (int e = t; e < 65*16; e += 1024){
    int node = e >> 4, u = e & 15;
    float4 r = make_float4(0.f,0.f,0.f,0.f);
    if (node < 64){
      const float4* c = (const float4*)(h + (size_t)(OFFS[4] + 4*node)*64) + u;
      float4 c0 = c[0], c1 = c[16], c2 = c[32], c3 = c[48];
      float4 pr = *((const float4*)(h + (size_t)(OFFS[3] + node)*64) + u);
      r.x = 0.25f*(c0.x+c1.x+c2.x+c3.x) + pr.x;
      r.y = 0.25f*(c0.y+c1.y+c2.y+c3.y) + pr.y;
      r.z = 0.25f*(c0.z+c1.z+c2.z+c3.z) + pr.z;
      r.w = 0.25f*(c0.w+c1.w+c2.w+c3.w) + pr.w;
    }
    unsigned short h0=f2bh(r.x), h1=f2bh(r.y), h2=f2bh(r.z), h3=f2bh(r.w);
    *(ushort4*)&PtH[node*72 + u*4] = make_ushort4(h0,h1,h2,h3);
    *(ushort4*)&PtL[node*72 + u*4] = make_ushort4(
        f2bh(r.x - bh2f(h0)), f2bh(r.y - bh2f(h1)),
        f2bh(r.z - bh2f(h2)), f2bh(r.w - bh2f(h3)));
  }
  __syncthreads();
  tail_level2<3>(h, WH + (size_t)2*36864, WLo + (size_t)2*36864, convB, Hpar, PtH, PtL, t);
  tail_level2<2>(h, WH + (size_t)1*36864, WLo + (size_t)1*36864, convB, Hpar, PtH, PtL, t);
  tail_level2<1>(h, WH,                   WLo,                   convB, Hpar, PtH, PtL, t);
  // epilogue: emb levels 0..4 (23 tile-jobs over 16 waves)
  for (int j = w; j < 23; j += 16){
    int d, tile;
    if (j < 16)      { d=4; tile=j;    }
    else if (j < 20) { d=3; tile=j-16; }
    else if (j == 20){ d=2; tile=0;    }
    else if (j == 21){ d=1; tile=0;    }
    else             { d=0; tile=0;    }
    int Nlev = 1 << (2*d);
    int valid = Nlev - tile*16;
    emb_tile(h, EH, ELo, embB, lng, lnb, gain, d,
             (size_t)OFFS[d] + (size_t)tile*16, valid > 16 ? 16 : valid, lane);
  }
}

extern "C" void kernel_launch(void* const* d_in, const int* in_sizes, int n_in,
                              void* d_out, int out_size, void* d_ws, size_t ws_size,
                              hipStream_t stream) {
  (void)in_sizes; (void)n_in; (void)out_size;
  const float* feat  = (const float*)d_in[0];
  const float* ipW   = (const float*)d_in[1];
  const float* ipB   = (const float*)d_in[2];
  const float* convW = (const float*)d_in[3];
  const float* convB = (const float*)d_in[4];
  const float* embW  = (const float*)d_in[5];
  const float* embB  = (const float*)d_in[6];
  const float* lng   = (const float*)d_in[7];
  const float* lnb   = (const float*)d_in[8];
  const float* gain  = (const float*)d_in[9];
  float* h = (float*)d_out;

  unsigned short* WH  = (unsigned short*)d_ws;
  unsigned short* WLo = WH + FRAG_USH;
  const unsigned short* EH  = WH  + CONV_USH;
  const unsigned short* ELo = WLo + CONV_USH;
  float* hpre = (ws_size >= FRAG_BYTES + HPRE_BYTES)
              ? (float*)((char*)d_ws + FRAG_BYTES) : nullptr;

  // 1: merged W-prep + inproj
  k_prep<<<WPREP_BLOCKS + INPROJ_BLOCKS, 256, 0, stream>>>(
      convW, embW, WH, WLo, feat, ipW, ipB, h, hpre);

  // 2..6: bare conv L=8..4
  for (int L = 8; L >= 4; --L){
    int Np = 1 << (2*L);
    const float* hPar = hpre ? (hpre + (size_t)(OFFS[L] - OFFS[4])*64)
                             : (h + (size_t)OFFS[L]*64);
    k_conv<<<Np/64, 256, 0, stream>>>(h, hPar,
        WH  + (size_t)(L-1)*36864, WLo + (size_t)(L-1)*36864,
        convB + (size_t)L*64, Np, OFFS[L], OFFS[L+1], L);
  }

  // 7: final — 16-wave tail + all emb (levels 5..9, 512-node blocks)
  k_final<<<1 + 682, 1024, 0, stream>>>(h, WH, WLo, convB,
      EH, ELo, embB, lng, lnb, gain);
}